// Round 4
// baseline (2926.871 us; speedup 1.0000x reference)
//
#include <hip/hip_runtime.h>
#include <hip/hip_bf16.h>

typedef __hip_bfloat16 bf16;

#define DI __device__ __forceinline__

DI float ldf(const float* p, long long i){ return p[i]; }
DI float ldf(const bf16* p, long long i){ return __bfloat162float(p[i]); }
DI void stf(float* p, long long i, float v){ p[i] = v; }
DI void stf(bf16* p, long long i, float v){ p[i] = __float2bfloat16(v); }

static constexpr int BATCH = 8;
static constexpr int HH = 56, WW = 56;
static constexpr int NPOS = HH * WW;        // 3136
static constexpr int CDIM = 256;
static constexpr int HIDD = 1024;
static constexpr int MTOT = BATCH * NPOS;   // 25088
static constexpr int NCHUNK = 49;           // 3136 / 64

// ---------------- LayerNorm ----------------
template<int C, typename TIN>
__global__ __launch_bounds__(256) void ln_kernel(const TIN* __restrict__ x, const float* __restrict__ g,
                                                 const float* __restrict__ b, float* __restrict__ y){
    constexpr int PT = C / 256;
    __shared__ float r1[256], r2[256];
    long long row = blockIdx.x;
    int tid = threadIdx.x;
    const TIN* xr = x + row * C;
    float v[PT]; float s = 0.f, ss = 0.f;
    #pragma unroll
    for (int i = 0; i < PT; i++){ v[i] = ldf(xr, tid + i*256); s += v[i]; ss += v[i]*v[i]; }
    r1[tid] = s; r2[tid] = ss; __syncthreads();
    for (int st = 128; st > 0; st >>= 1){
        if (tid < st){ r1[tid] += r1[tid+st]; r2[tid] += r2[tid+st]; }
        __syncthreads();
    }
    float mean = r1[0] * (1.f / C);
    float var  = r2[0] * (1.f / C) - mean*mean;
    float inv  = rsqrtf(var + 1e-5f);
    #pragma unroll
    for (int i = 0; i < PT; i++){
        int c = tid + i*256;
        y[row*C + c] = (v[i]-mean)*inv*g[c] + b[c];
    }
}

// ---------------- generic tiled GEMM ----------------
// out[m,n] = sum_k A[m,k] * (TRANSB ? B[n,k] : B[k,n]) + bias[n] + addend[m,n]
// batched via blockIdx.z with element strides strA/strB/strC/strAdd.
// In-place epilogue add (Cout == addend) is safe: each element read then
// written by the same thread, tiles disjoint.
template<bool TRANSB, typename TA, typename TB, typename TC, typename TADD>
__global__ __launch_bounds__(256) void gemm_kernel(
    const TA* __restrict__ A, const TB* __restrict__ Bm, const TB* __restrict__ bias,
    const TADD* __restrict__ addend, TC* __restrict__ Cout,
    int M, int N, int K, long long strA, long long strB, long long strC, long long strAdd)
{
    __shared__ float shA[16][65];
    __shared__ float shB[16][65];
    int tid = threadIdx.x;
    int bz = blockIdx.z;
    A  += (long long)bz * strA;
    Bm += (long long)bz * strB;
    Cout += (long long)bz * strC;
    if (addend) addend += (long long)bz * strAdd;
    int m0 = blockIdx.y * 64, n0 = blockIdx.x * 64;
    int ty = tid >> 4, tx = tid & 15;
    float acc[4][4] = {};
    for (int k0 = 0; k0 < K; k0 += 16){
        #pragma unroll
        for (int i = 0; i < 4; i++){
            int e = tid + i*256;
            int m = e >> 4, kk = e & 15;
            shA[kk][m] = ldf(A, (long long)(m0+m)*K + k0 + kk);
        }
        if (TRANSB){
            #pragma unroll
            for (int i = 0; i < 4; i++){
                int e = tid + i*256;
                int n = e >> 4, kk = e & 15;
                shB[kk][n] = ldf(Bm, (long long)(n0+n)*K + k0 + kk);
            }
        } else {
            #pragma unroll
            for (int i = 0; i < 4; i++){
                int e = tid + i*256;
                int n = e & 63, kk = e >> 6;
                shB[kk][n] = ldf(Bm, (long long)(k0+kk)*N + n0 + n);
            }
        }
        __syncthreads();
        #pragma unroll
        for (int kk = 0; kk < 16; kk++){
            float ra[4], rb[4];
            #pragma unroll
            for (int i = 0; i < 4; i++) ra[i] = shA[kk][ty*4+i];
            #pragma unroll
            for (int j = 0; j < 4; j++) rb[j] = shB[kk][tx*4+j];
            #pragma unroll
            for (int i = 0; i < 4; i++)
                #pragma unroll
                for (int j = 0; j < 4; j++)
                    acc[i][j] += ra[i]*rb[j];
        }
        __syncthreads();
    }
    #pragma unroll
    for (int i = 0; i < 4; i++){
        int m = m0 + ty*4 + i;
        #pragma unroll
        for (int j = 0; j < 4; j++){
            int n = n0 + tx*4 + j;
            float v = acc[i][j];
            if (bias)   v += ldf(bias, n);
            if (addend) v += ldf(addend, (long long)m*N + n);
            stf(Cout, (long long)m*N + n, v);
        }
    }
}

// ---------------- TN GEMM for ctx: C[i,j] = sum_n A[b,n,i]*B[b,n,j] ----------------
__global__ __launch_bounds__(256) void gemm_tn_kernel(const float* __restrict__ A, const float* __restrict__ B,
                                                      float* __restrict__ C){
    __shared__ float sA[32][33], sB[32][33];
    int bz = blockIdx.z;
    const float* Ab = A + (long long)bz * NPOS * CDIM;
    const float* Bb = B + (long long)bz * NPOS * CDIM;
    float* Cb = C + (long long)bz * CDIM * CDIM;
    int tid = threadIdx.x;
    int i0 = blockIdx.y * 32, j0 = blockIdx.x * 32;
    int ty = tid >> 5, tx = tid & 31;
    float acc[4] = {0.f,0.f,0.f,0.f};
    for (int n0 = 0; n0 < NPOS; n0 += 32){
        #pragma unroll
        for (int i = 0; i < 4; i++){
            int e = tid + i*256; int r = e >> 5, c = e & 31;
            sA[r][c] = Ab[(long long)(n0+r)*CDIM + i0 + c];
            sB[r][c] = Bb[(long long)(n0+r)*CDIM + j0 + c];
        }
        __syncthreads();
        #pragma unroll
        for (int r = 0; r < 32; r++){
            float bv = sB[r][tx];
            #pragma unroll
            for (int ii = 0; ii < 4; ii++) acc[ii] += sA[r][ty*4+ii]*bv;
        }
        __syncthreads();
    }
    #pragma unroll
    for (int ii = 0; ii < 4; ii++) Cb[(long long)(i0+ty*4+ii)*CDIM + j0 + tx] = acc[ii];
}

// ---------------- column softmax over N (for k), chunked two-phase ----------------
__global__ __launch_bounds__(256) void colsm_p1(const float* __restrict__ x, float* __restrict__ lmax, float* __restrict__ lsum){
    int b = blockIdx.x / NCHUNK, ch = blockIdx.x % NCHUNK;
    int c = threadIdx.x;
    const float* base = x + ((long long)b*NPOS + ch*64)*CDIM + c;
    float m = -1e30f;
    for (int r = 0; r < 64; r++) m = fmaxf(m, base[(long long)r*CDIM]);
    float s = 0.f;
    for (int r = 0; r < 64; r++) s += expf(base[(long long)r*CDIM] - m);
    lmax[(long long)blockIdx.x*CDIM + c] = m;
    lsum[(long long)blockIdx.x*CDIM + c] = s;
}
__global__ __launch_bounds__(256) void colsm_p2(const float* __restrict__ lmax, const float* __restrict__ lsum,
                                                float* __restrict__ gmax, float* __restrict__ ginv){
    int b = blockIdx.x; int c = threadIdx.x;
    float g = -1e30f;
    for (int ch = 0; ch < NCHUNK; ch++) g = fmaxf(g, lmax[((long long)b*NCHUNK+ch)*CDIM + c]);
    float s = 0.f;
    for (int ch = 0; ch < NCHUNK; ch++)
        s += lsum[((long long)b*NCHUNK+ch)*CDIM + c] * expf(lmax[((long long)b*NCHUNK+ch)*CDIM + c] - g);
    gmax[b*CDIM + c] = g; ginv[b*CDIM + c] = 1.f / s;
}
__global__ __launch_bounds__(256) void colsm_p3(float* __restrict__ x, const float* __restrict__ gmax, const float* __restrict__ ginv){
    long long idx = (long long)blockIdx.x*256 + threadIdx.x;
    int c = idx & (CDIM-1);
    int b = (int)(idx / ((long long)NPOS*CDIM));
    x[idx] = expf(x[idx] - gmax[b*CDIM + c]) * ginv[b*CDIM + c];
}

// ---------------- row softmax over C=256 (for q), in-place ----------------
__global__ __launch_bounds__(256) void rowsm_kernel(float* __restrict__ x){
    __shared__ float red[256];
    long long row = blockIdx.x;
    int tid = threadIdx.x;
    float v = x[row*256 + tid];
    red[tid] = v; __syncthreads();
    for (int st = 128; st > 0; st >>= 1){ if (tid < st) red[tid] = fmaxf(red[tid], red[tid+st]); __syncthreads(); }
    float m = red[0]; __syncthreads();
    float e = expf(v - m);
    red[tid] = e; __syncthreads();
    for (int st = 128; st > 0; st >>= 1){ if (tid < st) red[tid] += red[tid+st]; __syncthreads(); }
    x[row*256 + tid] = e / red[0];
}

// ---------------- fused dwconv3x3 + skip + LN + GELU (C=1024, one row per block) ----------------
__global__ __launch_bounds__(256) void dwconv_ln_gelu_kernel(const bf16* __restrict__ f, const float* __restrict__ dw,
        const float* __restrict__ db, const float* __restrict__ lg, const float* __restrict__ lb, bf16* __restrict__ out){
    __shared__ float r1[256], r2[256];
    int n = blockIdx.x;
    int b = n / NPOS, hw = n % NPOS;
    int h = hw / WW, w = hw % WW;
    int tid = threadIdx.x;
    const bf16* fb = f + (long long)b * NPOS * HIDD;
    float sv[4]; float s = 0.f, ss = 0.f;
    #pragma unroll
    for (int j = 0; j < 4; j++){
        int c = tid + j*256;
        float acc = db[c] + __bfloat162float(fb[(long long)hw*HIDD + c]);  // bias + skip
        #pragma unroll
        for (int ky = 0; ky < 3; ky++){
            int hy = h + ky - 1;
            if (hy < 0 || hy >= HH) continue;
            #pragma unroll
            for (int kx = 0; kx < 3; kx++){
                int wx = w + kx - 1;
                if (wx < 0 || wx >= WW) continue;
                acc += __bfloat162float(fb[(long long)(hy*WW + wx)*HIDD + c]) * dw[c*9 + ky*3 + kx];
            }
        }
        sv[j] = acc; s += acc; ss += acc*acc;
    }
    r1[tid] = s; r2[tid] = ss; __syncthreads();
    for (int st = 128; st > 0; st >>= 1){
        if (tid < st){ r1[tid] += r1[tid+st]; r2[tid] += r2[tid+st]; }
        __syncthreads();
    }
    float mean = r1[0] * (1.f/HIDD);
    float var  = r2[0] * (1.f/HIDD) - mean*mean;
    float inv  = rsqrtf(var + 1e-5f);
    #pragma unroll
    for (int j = 0; j < 4; j++){
        int c = tid + j*256;
        float o = (sv[j]-mean)*inv*lg[c] + lb[c];
        o = 0.5f*o*(1.f + erff(o*0.70710678118654752f));
        out[(long long)n*HIDD + c] = __float2bfloat16(o);
    }
}

// ---------------- channel-attn: per-channel L2 norms over N (channels 0..511 of qkv) ----------------
__global__ __launch_bounds__(256) void ssq_p1(const bf16* __restrict__ qkv, float* __restrict__ lss){
    int b = blockIdx.x / NCHUNK, ch = blockIdx.x % NCHUNK;
    int c = blockIdx.y*256 + threadIdx.x;   // 0..511
    const bf16* base = qkv + ((long long)b*NPOS + ch*64)*768 + c;
    float s = 0.f;
    for (int r = 0; r < 64; r++){ float v = __bfloat162float(base[(long long)r*768]); s += v*v; }
    lss[(long long)blockIdx.x*512 + c] = s;
}
__global__ __launch_bounds__(256) void ssq_p2(const float* __restrict__ lss, float* __restrict__ invn){
    int b = blockIdx.x; int c = blockIdx.y*256 + threadIdx.x;
    float s = 0.f;
    for (int ch = 0; ch < NCHUNK; ch++) s += lss[((long long)b*NCHUNK+ch)*512 + c];
    invn[b*512 + c] = 1.f / fmaxf(sqrtf(s), 1e-12f);
}

// ---------------- channel-attn: attn[b,h,d,e] = softmax_e(temp[h] * q_d . k_e) ----------------
__global__ __launch_bounds__(256) void chanattn_qk(const bf16* __restrict__ qkv, const float* __restrict__ invn,
                                                   const float* __restrict__ temp, float* __restrict__ attn){
    __shared__ float qs[64][33];
    __shared__ float ks[64][33];
    __shared__ float att_s[32][33];
    int b = blockIdx.x >> 3, hh = blockIdx.x & 7;
    int tid = threadIdx.x;
    int d = tid >> 3, e0 = (tid & 7) * 4;
    float acc[4] = {0.f,0.f,0.f,0.f};
    for (int n0 = 0; n0 < NPOS; n0 += 64){
        #pragma unroll
        for (int i = 0; i < 8; i++){
            int e = tid + i*256; int r = e >> 5, c = e & 31;
            long long rowb = (long long)(b*NPOS + n0 + r) * 768;
            qs[r][c] = __bfloat162float(qkv[rowb + hh*32 + c])       * invn[b*512 + hh*32 + c];
            ks[r][c] = __bfloat162float(qkv[rowb + 256 + hh*32 + c]) * invn[b*512 + 256 + hh*32 + c];
        }
        __syncthreads();
        #pragma unroll 4
        for (int r = 0; r < 64; r++){
            float qv = qs[r][d];
            #pragma unroll
            for (int j = 0; j < 4; j++) acc[j] += qv * ks[r][e0+j];
        }
        __syncthreads();
    }
    float t = temp[hh];
    #pragma unroll
    for (int j = 0; j < 4; j++) att_s[d][e0+j] = acc[j] * t;
    __syncthreads();
    if (tid < 32){
        float m = -1e30f;
        for (int e = 0; e < 32; e++) m = fmaxf(m, att_s[tid][e]);
        float s = 0.f;
        for (int e = 0; e < 32; e++){ float ev = expf(att_s[tid][e] - m); att_s[tid][e] = ev; s += ev; }
        float inv = 1.f / s;
        for (int e = 0; e < 32; e++) att_s[tid][e] *= inv;
    }
    __syncthreads();
    #pragma unroll
    for (int j = 0; j < 4; j++)
        attn[(((long long)(b*8+hh))*32 + d)*32 + e0 + j] = att_s[d][e0+j];
}

// ---------------- channel-attn: out[b,n,c] = sum_e attn[b,h,d,e] * v[b,n,h*32+e] ----------------
__global__ __launch_bounds__(256) void chanattn_av(const bf16* __restrict__ qkv, const float* __restrict__ attn,
                                                   float* __restrict__ out){
    __shared__ float vsh[256];
    long long n = blockIdx.x;
    int b = (int)(n / NPOS);
    int c = threadIdx.x;
    vsh[c] = __bfloat162float(qkv[n*768 + 512 + c]);
    __syncthreads();
    int hh = c >> 5;
    const float* arow = attn + ((long long)(b*8+hh)*32 + (c & 31))*32;
    float s = 0.f;
    #pragma unroll
    for (int e = 0; e < 32; e++) s += arow[e] * vsh[hh*32 + e];
    out[n*256 + c] = s;
}

// ---------------- orchestration ----------------
extern "C" void kernel_launch(void* const* d_in, const int* in_sizes, int n_in,
                              void* d_out, int out_size, void* d_ws, size_t ws_size,
                              hipStream_t stream){
    // Inputs are FLOAT32 per the reference (setup_inputs is all jnp.float32).
    // (R0-R3 read them as bf16 -> garbage/NaN; harness contract says dtype
    //  follows the reference.)
    const float* x     = (const float*)d_in[0];
    const float* ln1g  = (const float*)d_in[3];
    const float* ln1b  = (const float*)d_in[4];
    const float* eakw  = (const float*)d_in[5];
    const float* eakb  = (const float*)d_in[6];
    const float* eaqw  = (const float*)d_in[7];
    const float* eaqb  = (const float*)d_in[8];
    const float* eavw  = (const float*)d_in[9];
    const float* eavb  = (const float*)d_in[10];
    const float* earw  = (const float*)d_in[11];
    const float* earb  = (const float*)d_in[12];
    const float* ln2g  = (const float*)d_in[13];
    const float* ln2b  = (const float*)d_in[14];
    const float* m1w1  = (const float*)d_in[15];
    const float* m1b1  = (const float*)d_in[16];
    const float* m1dww = (const float*)d_in[17];
    const float* m1dwb = (const float*)d_in[18];
    const float* m1lg  = (const float*)d_in[19];
    const float* m1lb  = (const float*)d_in[20];
    const float* m1w2  = (const float*)d_in[21];
    const float* m1b2  = (const float*)d_in[22];
    const float* ln3g  = (const float*)d_in[23];
    const float* ln3b  = (const float*)d_in[24];
    const float* catemp= (const float*)d_in[25];
    const float* caqkvw= (const float*)d_in[26];
    const float* capw  = (const float*)d_in[27];
    const float* capb  = (const float*)d_in[28];
    const float* ln4g  = (const float*)d_in[29];
    const float* ln4b  = (const float*)d_in[30];
    const float* m2w1  = (const float*)d_in[31];
    const float* m2b1  = (const float*)d_in[32];
    const float* m2dww = (const float*)d_in[33];
    const float* m2dwb = (const float*)d_in[34];
    const float* m2lg  = (const float*)d_in[35];
    const float* m2lb  = (const float*)d_in[36];
    const float* m2w2  = (const float*)d_in[37];
    const float* m2b2  = (const float*)d_in[38];

    // ---- Workspace carve: ~133 MB total (known safe: 209 MB didn't fault).
    //   R            : persistent f32 residual stream
    //   A0,A1,B0,B1  : 4x f32 (contiguous; SZ bytes each, 256-aligned)
    //     stage 1: A0=ln, B0=k, B1=q, A1=v, att->B0
    //     stage 2/4: F=(bf16*)B0 spans B0B1; G=(bf16*)A0 spans A0A1
    //     stage 3: ln->A0, qkv=(bf16*)B0 (38.5 MB), attn-out->A1
    char* base = (char*)d_ws;
    auto alloc = [&](size_t nbytes){ char* p = base; base += (nbytes + 255) & ~(size_t)255; return p; };
    constexpr size_t SZ = (size_t)MTOT*CDIM*4;   // 25,690,112 (multiple of 256)
    float* R  = (float*)alloc(SZ);
    float* A0 = (float*)alloc(SZ);
    float* A1 = (float*)alloc(SZ);
    float* B0 = (float*)alloc(SZ);
    float* B1 = (float*)alloc(SZ);
    bf16*  F  = (bf16*)B0;    // MTOT*HIDD bf16 = 51.4 MB, spans B0..B1 exactly
    bf16*  G  = (bf16*)A0;    // spans A0..A1 exactly
    bf16*  Q  = (bf16*)B0;    // MTOT*768 bf16 = 38.5 MB, fits in B-span
    float* ctxb = (float*)alloc((size_t)BATCH*CDIM*CDIM*4);
    float* lmax = (float*)alloc((size_t)BATCH*NCHUNK*CDIM*4);
    float* lsum = (float*)alloc((size_t)BATCH*NCHUNK*CDIM*4);
    float* gmax = (float*)alloc((size_t)BATCH*CDIM*4);
    float* ginv = (float*)alloc((size_t)BATCH*CDIM*4);
    float* lss  = (float*)alloc((size_t)BATCH*NCHUNK*512*4);
    float* invn = (float*)alloc((size_t)BATCH*512*4);
    float* attnb= (float*)alloc((size_t)BATCH*8*32*32*4);

    dim3 blk(256);
    long long sAB = (long long)NPOS*CDIM;

    // ---- Stage 1: EfficientAttention ----
    ln_kernel<256, float><<<MTOT, blk, 0, stream>>>(x, ln1g, ln1b, A0);
    gemm_kernel<true, float, float, float, float><<<dim3(4,392,1), blk, 0, stream>>>(A0, eakw, eakb, nullptr, B0, MTOT, 256, 256, 0,0,0,0); // k
    gemm_kernel<true, float, float, float, float><<<dim3(4,392,1), blk, 0, stream>>>(A0, eaqw, eaqb, nullptr, B1, MTOT, 256, 256, 0,0,0,0); // q
    gemm_kernel<true, float, float, float, float><<<dim3(4,392,1), blk, 0, stream>>>(A0, eavw, eavb, nullptr, A1, MTOT, 256, 256, 0,0,0,0); // v
    rowsm_kernel<<<MTOT, blk, 0, stream>>>(B1);                         // q softmax (channels)
    colsm_p1<<<BATCH*NCHUNK, blk, 0, stream>>>(B0, lmax, lsum);         // k softmax (spatial)
    colsm_p2<<<BATCH, blk, 0, stream>>>(lmax, lsum, gmax, ginv);
    colsm_p3<<<MTOT, blk, 0, stream>>>(B0, gmax, ginv);
    gemm_tn_kernel<<<dim3(8,8,BATCH), blk, 0, stream>>>(B0, A1, ctxb);  // ctx = k^T v
    gemm_kernel<false, float, float, float, float><<<dim3(4,49,BATCH), blk, 0, stream>>>(B1, ctxb, nullptr, nullptr, B0,
            NPOS, 256, 256, sAB, (long long)CDIM*CDIM, sAB, 0);         // att = q @ ctx  (overwrites dead k)
    gemm_kernel<true, float, float, float, float><<<dim3(4,392,1), blk, 0, stream>>>(B0, earw, earb, x, R, MTOT, 256, 256, 0,0,0,0); // R = x + proj

    // ---- Stage 2: MixFFN #1 ----
    ln_kernel<256, float><<<MTOT, blk, 0, stream>>>(R, ln2g, ln2b, A1);
    gemm_kernel<true, float, float, bf16, float><<<dim3(16,392,1), blk, 0, stream>>>(A1, m1w1, m1b1, nullptr, F, MTOT, 1024, 256, 0,0,0,0);
    dwconv_ln_gelu_kernel<<<MTOT, blk, 0, stream>>>(F, m1dww, m1dwb, m1lg, m1lb, G);   // reads B-span, writes A-span (A1 dead)
    gemm_kernel<true, bf16, float, float, float><<<dim3(4,392,1), blk, 0, stream>>>(G, m1w2, m1b2, R, R, MTOT, 256, 1024, 0,0,0,0); // R += ffn (in-place)

    // ---- Stage 3: ChannelAttention ----
    ln_kernel<256, float><<<MTOT, blk, 0, stream>>>(R, ln3g, ln3b, A0);
    gemm_kernel<true, float, float, bf16, float><<<dim3(12,392,1), blk, 0, stream>>>(A0, caqkvw, nullptr, nullptr, Q, MTOT, 768, 256, 0,0,0,0);
    ssq_p1<<<dim3(BATCH*NCHUNK,2), blk, 0, stream>>>(Q, lss);
    ssq_p2<<<dim3(BATCH,2), blk, 0, stream>>>(lss, invn);
    chanattn_qk<<<BATCH*8, blk, 0, stream>>>(Q, invn, catemp, attnb);
    chanattn_av<<<MTOT, blk, 0, stream>>>(Q, attnb, A1);
    gemm_kernel<true, float, float, float, float><<<dim3(4,392,1), blk, 0, stream>>>(A1, capw, capb, R, R, MTOT, 256, 256, 0,0,0,0); // R += proj (in-place)

    // ---- Stage 4: MixFFN #2 ----
    ln_kernel<256, float><<<MTOT, blk, 0, stream>>>(R, ln4g, ln4b, A1);
    gemm_kernel<true, float, float, bf16, float><<<dim3(16,392,1), blk, 0, stream>>>(A1, m2w1, m2b1, nullptr, F, MTOT, 1024, 256, 0,0,0,0);
    dwconv_ln_gelu_kernel<<<MTOT, blk, 0, stream>>>(F, m2dww, m2dwb, m2lg, m2lb, G);
    gemm_kernel<true, bf16, float, float, float><<<dim3(4,392,1), blk, 0, stream>>>(G, m2w2, m2b2, R, (float*)d_out, MTOT, 256, 1024, 0,0,0,0);
}

// Round 5
// 1547.195 us; speedup vs baseline: 1.8917x; 1.8917x over previous
//
#include <hip/hip_runtime.h>
#include <hip/hip_bf16.h>

typedef __hip_bfloat16 bf16;
typedef __attribute__((ext_vector_type(8))) short short8;
typedef __attribute__((ext_vector_type(4))) float floatx4;

#define DI __device__ __forceinline__

DI float ldf(const float* p, long long i){ return p[i]; }
DI float ldf(const bf16* p, long long i){ return __bfloat162float(p[i]); }
DI void stf(float* p, long long i, float v){ p[i] = v; }
DI void stf(bf16* p, long long i, float v){ p[i] = __float2bfloat16(v); }

DI unsigned short bfbits(float f){
    bf16 h = __float2bfloat16(f);
    return *reinterpret_cast<unsigned short*>(&h);
}

static constexpr int BATCH = 8;
static constexpr int HH = 56, WW = 56;
static constexpr int NPOS = HH * WW;        // 3136
static constexpr int CDIM = 256;
static constexpr int HIDD = 1024;
static constexpr int MTOT = BATCH * NPOS;   // 25088
static constexpr int NCHUNK = 49;           // 3136 / 64
static constexpr int LP = 40;               // LDS row pitch (shorts): breaks 8-row bank aliasing

// ---------------- MFMA bf16 GEMM ----------------
// out[m,n] = sum_k A[m,k](bf16) * Bw[n,k](f32->bf16) + bias[n] + addend[m,n]
// 128x128 block tile, BK=32, 4 waves of 64x64 (4x4 mfma_f32_16x16x32_bf16).
// Batched via blockIdx.z (element strides). M may be non-multiple of 128 (guarded).
template<typename TC>
__global__ __launch_bounds__(256) void mfma_gemm(
    const bf16* __restrict__ A, const float* __restrict__ Bw,
    const float* __restrict__ bias, const float* __restrict__ addend,
    TC* __restrict__ C, int M, int N, int K,
    long long strA, long long strB, long long strC, long long strAdd)
{
    __shared__ short As[128*LP];
    __shared__ short Bs[128*LP];
    int tid = threadIdx.x;
    int bz = blockIdx.z;
    A  += (long long)bz * strA;
    Bw += (long long)bz * strB;
    C  += (long long)bz * strC;
    if (addend) addend += (long long)bz * strAdd;
    int n0 = blockIdx.x * 128, m0 = blockIdx.y * 128;
    int w = tid >> 6, lane = tid & 63, lm = lane & 15, quad = lane >> 4;
    int mw = (w >> 1) * 64, nw = (w & 1) * 64;

    floatx4 z = {0.f, 0.f, 0.f, 0.f};
    floatx4 acc[4][4];
    #pragma unroll
    for (int mi = 0; mi < 4; mi++)
        #pragma unroll
        for (int ni = 0; ni < 4; ni++) acc[mi][ni] = z;

    // B staging coords: thread t -> row n=t>>1, half h=t&1 (16 f32 -> 16 bf16)
    int bn = tid >> 1, bh = tid & 1;

    for (int k0 = 0; k0 < K; k0 += 32){
        // ---- stage A (bf16, 128x32): 512 16B-chunks, 2 per thread ----
        #pragma unroll
        for (int cc = 0; cc < 2; cc++){
            int c = tid + cc*256;
            int row = c >> 2, col8 = (c & 3) * 8;
            int rg = m0 + row; if (rg > M-1) rg = M-1;
            uint4 v = *(const uint4*)(A + (long long)rg*K + k0 + col8);
            *(uint4*)&As[row*LP + col8] = v;
        }
        // ---- stage B (f32 -> bf16, 128x32) ----
        {
            const float* src = Bw + (long long)(n0 + bn)*K + k0 + bh*16;
            float4 f0 = *(const float4*)(src);
            float4 f1 = *(const float4*)(src + 4);
            float4 f2 = *(const float4*)(src + 8);
            float4 f3 = *(const float4*)(src + 12);
            union { uint4 u4; unsigned short us[8]; } p0, p1;
            p0.us[0]=bfbits(f0.x); p0.us[1]=bfbits(f0.y); p0.us[2]=bfbits(f0.z); p0.us[3]=bfbits(f0.w);
            p0.us[4]=bfbits(f1.x); p0.us[5]=bfbits(f1.y); p0.us[6]=bfbits(f1.z); p0.us[7]=bfbits(f1.w);
            p1.us[0]=bfbits(f2.x); p1.us[1]=bfbits(f2.y); p1.us[2]=bfbits(f2.z); p1.us[3]=bfbits(f2.w);
            p1.us[4]=bfbits(f3.x); p1.us[5]=bfbits(f3.y); p1.us[6]=bfbits(f3.z); p1.us[7]=bfbits(f3.w);
            *(uint4*)&Bs[bn*LP + bh*16]     = p0.u4;
            *(uint4*)&Bs[bn*LP + bh*16 + 8] = p1.u4;
        }
        __syncthreads();
        // ---- MFMA: 8 ds_read_b128 + 16 mfma per wave ----
        short8 af[4], bfr[4];
        #pragma unroll
        for (int mi = 0; mi < 4; mi++)
            af[mi] = *(const short8*)&As[(mw + mi*16 + lm)*LP + quad*8];
        #pragma unroll
        for (int ni = 0; ni < 4; ni++)
            bfr[ni] = *(const short8*)&Bs[(nw + ni*16 + lm)*LP + quad*8];
        #pragma unroll
        for (int mi = 0; mi < 4; mi++)
            #pragma unroll
            for (int ni = 0; ni < 4; ni++)
                acc[mi][ni] = __builtin_amdgcn_mfma_f32_16x16x32_bf16(af[mi], bfr[ni], acc[mi][ni], 0, 0, 0);
        __syncthreads();
    }

    // ---- epilogue: C/D layout col=lane&15, row=quad*4+reg ----
    #pragma unroll
    for (int ni = 0; ni < 4; ni++){
        int cg = n0 + nw + ni*16 + lm;
        float bv = bias ? bias[cg] : 0.f;
        #pragma unroll
        for (int mi = 0; mi < 4; mi++){
            #pragma unroll
            for (int r = 0; r < 4; r++){
                int rg = m0 + mw + mi*16 + quad*4 + r;
                if (rg < M){
                    long long idx = (long long)rg*N + cg;
                    float v = acc[mi][ni][r] + bv;
                    if (addend) v += addend[idx];
                    stf(C, idx, v);
                }
            }
        }
    }
}

// ---------------- LayerNorm (f32 in, TOUT out) ----------------
template<int C, typename TIN, typename TOUT>
__global__ __launch_bounds__(256) void ln_kernel(const TIN* __restrict__ x, const float* __restrict__ g,
                                                 const float* __restrict__ b, TOUT* __restrict__ y){
    constexpr int PT = C / 256;
    __shared__ float r1[256], r2[256];
    long long row = blockIdx.x;
    int tid = threadIdx.x;
    const TIN* xr = x + row * C;
    float v[PT]; float s = 0.f, ss = 0.f;
    #pragma unroll
    for (int i = 0; i < PT; i++){ v[i] = ldf(xr, tid + i*256); s += v[i]; ss += v[i]*v[i]; }
    r1[tid] = s; r2[tid] = ss; __syncthreads();
    for (int st = 128; st > 0; st >>= 1){
        if (tid < st){ r1[tid] += r1[tid+st]; r2[tid] += r2[tid+st]; }
        __syncthreads();
    }
    float mean = r1[0] * (1.f / C);
    float var  = r2[0] * (1.f / C) - mean*mean;
    float inv  = rsqrtf(var + 1e-5f);
    #pragma unroll
    for (int i = 0; i < PT; i++){
        int c = tid + i*256;
        stf(y, row*C + c, (v[i]-mean)*inv*g[c] + b[c]);
    }
}

// ---------------- TN GEMM: C[b,i,j] = sum_n A[b,n,i]*B[b,n,j] (f32) ----------------
__global__ __launch_bounds__(256) void gemm_tn_kernel(const float* __restrict__ A, const float* __restrict__ B,
                                                      float* __restrict__ C){
    __shared__ float sA[32][33], sB[32][33];
    int bz = blockIdx.z;
    const float* Ab = A + (long long)bz * NPOS * CDIM;
    const float* Bb = B + (long long)bz * NPOS * CDIM;
    float* Cb = C + (long long)bz * CDIM * CDIM;
    int tid = threadIdx.x;
    int i0 = blockIdx.y * 32, j0 = blockIdx.x * 32;
    int ty = tid >> 5, tx = tid & 31;
    float acc[4] = {0.f,0.f,0.f,0.f};
    for (int n0 = 0; n0 < NPOS; n0 += 32){
        #pragma unroll
        for (int i = 0; i < 4; i++){
            int e = tid + i*256; int r = e >> 5, c = e & 31;
            sA[r][c] = Ab[(long long)(n0+r)*CDIM + i0 + c];
            sB[r][c] = Bb[(long long)(n0+r)*CDIM + j0 + c];
        }
        __syncthreads();
        #pragma unroll
        for (int r = 0; r < 32; r++){
            float bv = sB[r][tx];
            #pragma unroll
            for (int ii = 0; ii < 4; ii++) acc[ii] += sA[r][ty*4+ii]*bv;
        }
        __syncthreads();
    }
    #pragma unroll
    for (int ii = 0; ii < 4; ii++) Cb[(long long)(i0+ty*4+ii)*CDIM + j0 + tx] = acc[ii];
}

// ---------------- column softmax over N (for k), chunked two-phase ----------------
__global__ __launch_bounds__(256) void colsm_p1(const float* __restrict__ x, float* __restrict__ lmax, float* __restrict__ lsum){
    int b = blockIdx.x / NCHUNK, ch = blockIdx.x % NCHUNK;
    int c = threadIdx.x;
    const float* base = x + ((long long)b*NPOS + ch*64)*CDIM + c;
    float m = -1e30f;
    for (int r = 0; r < 64; r++) m = fmaxf(m, base[(long long)r*CDIM]);
    float s = 0.f;
    for (int r = 0; r < 64; r++) s += expf(base[(long long)r*CDIM] - m);
    lmax[(long long)blockIdx.x*CDIM + c] = m;
    lsum[(long long)blockIdx.x*CDIM + c] = s;
}
__global__ __launch_bounds__(256) void colsm_p2(const float* __restrict__ lmax, const float* __restrict__ lsum,
                                                float* __restrict__ gmax, float* __restrict__ ginv){
    int b = blockIdx.x; int c = threadIdx.x;
    float g = -1e30f;
    for (int ch = 0; ch < NCHUNK; ch++) g = fmaxf(g, lmax[((long long)b*NCHUNK+ch)*CDIM + c]);
    float s = 0.f;
    for (int ch = 0; ch < NCHUNK; ch++)
        s += lsum[((long long)b*NCHUNK+ch)*CDIM + c] * expf(lmax[((long long)b*NCHUNK+ch)*CDIM + c] - g);
    gmax[b*CDIM + c] = g; ginv[b*CDIM + c] = 1.f / s;
}
__global__ __launch_bounds__(256) void colsm_p3(float* __restrict__ x, const float* __restrict__ gmax, const float* __restrict__ ginv){
    long long idx = (long long)blockIdx.x*256 + threadIdx.x;
    int c = idx & (CDIM-1);
    int b = (int)(idx / ((long long)NPOS*CDIM));
    x[idx] = expf(x[idx] - gmax[b*CDIM + c]) * ginv[b*CDIM + c];
}

// ---------------- row softmax over C=256 (for q): f32 in, bf16 out ----------------
__global__ __launch_bounds__(256) void rowsm_kernel(const float* __restrict__ x, bf16* __restrict__ y){
    __shared__ float red[256];
    long long row = blockIdx.x;
    int tid = threadIdx.x;
    float v = x[row*256 + tid];
    red[tid] = v; __syncthreads();
    for (int st = 128; st > 0; st >>= 1){ if (tid < st) red[tid] = fmaxf(red[tid], red[tid+st]); __syncthreads(); }
    float m = red[0]; __syncthreads();
    float e = expf(v - m);
    red[tid] = e; __syncthreads();
    for (int st = 128; st > 0; st >>= 1){ if (tid < st) red[tid] += red[tid+st]; __syncthreads(); }
    y[row*256 + tid] = __float2bfloat16(e / red[0]);
}

// ---------------- fused dwconv3x3 + skip + LN + GELU (C=1024, one row per block) ----------------
__global__ __launch_bounds__(256) void dwconv_ln_gelu_kernel(const bf16* __restrict__ f, const float* __restrict__ dw,
        const float* __restrict__ db, const float* __restrict__ lg, const float* __restrict__ lb, bf16* __restrict__ out){
    __shared__ float r1[256], r2[256];
    int n = blockIdx.x;
    int b = n / NPOS, hw = n % NPOS;
    int h = hw / WW, w = hw % WW;
    int tid = threadIdx.x;
    const bf16* fb = f + (long long)b * NPOS * HIDD;
    float sv[4]; float s = 0.f, ss = 0.f;
    #pragma unroll
    for (int j = 0; j < 4; j++){
        int c = tid + j*256;
        float acc = db[c] + __bfloat162float(fb[(long long)hw*HIDD + c]);  // bias + skip
        #pragma unroll
        for (int ky = 0; ky < 3; ky++){
            int hy = h + ky - 1;
            if (hy < 0 || hy >= HH) continue;
            #pragma unroll
            for (int kx = 0; kx < 3; kx++){
                int wx = w + kx - 1;
                if (wx < 0 || wx >= WW) continue;
                acc += __bfloat162float(fb[(long long)(hy*WW + wx)*HIDD + c]) * dw[c*9 + ky*3 + kx];
            }
        }
        sv[j] = acc; s += acc; ss += acc*acc;
    }
    r1[tid] = s; r2[tid] = ss; __syncthreads();
    for (int st = 128; st > 0; st >>= 1){
        if (tid < st){ r1[tid] += r1[tid+st]; r2[tid] += r2[tid+st]; }
        __syncthreads();
    }
    float mean = r1[0] * (1.f/HIDD);
    float var  = r2[0] * (1.f/HIDD) - mean*mean;
    float inv  = rsqrtf(var + 1e-5f);
    #pragma unroll
    for (int j = 0; j < 4; j++){
        int c = tid + j*256;
        float o = (sv[j]-mean)*inv*lg[c] + lb[c];
        o = 0.5f*o*(1.f + erff(o*0.70710678118654752f));
        out[(long long)n*HIDD + c] = __float2bfloat16(o);
    }
}

// ---------------- channel-attn: per-channel L2 norms over N ----------------
__global__ __launch_bounds__(256) void ssq_p1(const bf16* __restrict__ qkv, float* __restrict__ lss){
    int b = blockIdx.x / NCHUNK, ch = blockIdx.x % NCHUNK;
    int c = blockIdx.y*256 + threadIdx.x;   // 0..511
    const bf16* base = qkv + ((long long)b*NPOS + ch*64)*768 + c;
    float s = 0.f;
    for (int r = 0; r < 64; r++){ float v = __bfloat162float(base[(long long)r*768]); s += v*v; }
    lss[(long long)blockIdx.x*512 + c] = s;
}
__global__ __launch_bounds__(256) void ssq_p2(const float* __restrict__ lss, float* __restrict__ invn){
    int b = blockIdx.x; int c = blockIdx.y*256 + threadIdx.x;
    float s = 0.f;
    for (int ch = 0; ch < NCHUNK; ch++) s += lss[((long long)b*NCHUNK+ch)*512 + c];
    invn[b*512 + c] = 1.f / fmaxf(sqrtf(s), 1e-12f);
}

// ---------------- channel-attn: attn[b,h,d,e] = softmax_e(temp[h] * q_d . k_e) ----------------
__global__ __launch_bounds__(256) void chanattn_qk(const bf16* __restrict__ qkv, const float* __restrict__ invn,
                                                   const float* __restrict__ temp, float* __restrict__ attn){
    __shared__ float qs[64][33];
    __shared__ float ks[64][33];
    __shared__ float att_s[32][33];
    int b = blockIdx.x >> 3, hh = blockIdx.x & 7;
    int tid = threadIdx.x;
    int d = tid >> 3, e0 = (tid & 7) * 4;
    float acc[4] = {0.f,0.f,0.f,0.f};
    for (int n0 = 0; n0 < NPOS; n0 += 64){
        #pragma unroll
        for (int i = 0; i < 8; i++){
            int e = tid + i*256; int r = e >> 5, c = e & 31;
            long long rowb = (long long)(b*NPOS + n0 + r) * 768;
            qs[r][c] = __bfloat162float(qkv[rowb + hh*32 + c])       * invn[b*512 + hh*32 + c];
            ks[r][c] = __bfloat162float(qkv[rowb + 256 + hh*32 + c]) * invn[b*512 + 256 + hh*32 + c];
        }
        __syncthreads();
        #pragma unroll 4
        for (int r = 0; r < 64; r++){
            float qv = qs[r][d];
            #pragma unroll
            for (int j = 0; j < 4; j++) acc[j] += qv * ks[r][e0+j];
        }
        __syncthreads();
    }
    float t = temp[hh];
    #pragma unroll
    for (int j = 0; j < 4; j++) att_s[d][e0+j] = acc[j] * t;
    __syncthreads();
    if (tid < 32){
        float m = -1e30f;
        for (int e = 0; e < 32; e++) m = fmaxf(m, att_s[tid][e]);
        float s = 0.f;
        for (int e = 0; e < 32; e++){ float ev = expf(att_s[tid][e] - m); att_s[tid][e] = ev; s += ev; }
        float inv = 1.f / s;
        for (int e = 0; e < 32; e++) att_s[tid][e] *= inv;
    }
    __syncthreads();
    #pragma unroll
    for (int j = 0; j < 4; j++)
        attn[(((long long)(b*8+hh))*32 + d)*32 + e0 + j] = att_s[d][e0+j];
}

// ---------------- channel-attn: out[b,n,c] = sum_e attn[b,h,d,e] * v[b,n,h*32+e] (bf16 out) ----------------
__global__ __launch_bounds__(256) void chanattn_av(const bf16* __restrict__ qkv, const float* __restrict__ attn,
                                                   bf16* __restrict__ out){
    __shared__ float vsh[256];
    long long n = blockIdx.x;
    int b = (int)(n / NPOS);
    int c = threadIdx.x;
    vsh[c] = __bfloat162float(qkv[n*768 + 512 + c]);
    __syncthreads();
    int hh = c >> 5;
    const float* arow = attn + ((long long)(b*8+hh)*32 + (c & 31))*32;
    float s = 0.f;
    #pragma unroll
    for (int e = 0; e < 32; e++) s += arow[e] * vsh[hh*32 + e];
    out[n*256 + c] = __float2bfloat16(s);
}

// ---------------- orchestration ----------------
extern "C" void kernel_launch(void* const* d_in, const int* in_sizes, int n_in,
                              void* d_out, int out_size, void* d_ws, size_t ws_size,
                              hipStream_t stream){
    const float* x     = (const float*)d_in[0];
    const float* ln1g  = (const float*)d_in[3];
    const float* ln1b  = (const float*)d_in[4];
    const float* eakw  = (const float*)d_in[5];
    const float* eakb  = (const float*)d_in[6];
    const float* eaqw  = (const float*)d_in[7];
    const float* eaqb  = (const float*)d_in[8];
    const float* eavw  = (const float*)d_in[9];
    const float* eavb  = (const float*)d_in[10];
    const float* earw  = (const float*)d_in[11];
    const float* earb  = (const float*)d_in[12];
    const float* ln2g  = (const float*)d_in[13];
    const float* ln2b  = (const float*)d_in[14];
    const float* m1w1  = (const float*)d_in[15];
    const float* m1b1  = (const float*)d_in[16];
    const float* m1dww = (const float*)d_in[17];
    const float* m1dwb = (const float*)d_in[18];
    const float* m1lg  = (const float*)d_in[19];
    const float* m1lb  = (const float*)d_in[20];
    const float* m1w2  = (const float*)d_in[21];
    const float* m1b2  = (const float*)d_in[22];
    const float* ln3g  = (const float*)d_in[23];
    const float* ln3b  = (const float*)d_in[24];
    const float* catemp= (const float*)d_in[25];
    const float* caqkvw= (const float*)d_in[26];
    const float* capw  = (const float*)d_in[27];
    const float* capb  = (const float*)d_in[28];
    const float* ln4g  = (const float*)d_in[29];
    const float* ln4b  = (const float*)d_in[30];
    const float* m2w1  = (const float*)d_in[31];
    const float* m2b1  = (const float*)d_in[32];
    const float* m2dww = (const float*)d_in[33];
    const float* m2dwb = (const float*)d_in[34];
    const float* m2lg  = (const float*)d_in[35];
    const float* m2lb  = (const float*)d_in[36];
    const float* m2w2  = (const float*)d_in[37];
    const float* m2b2  = (const float*)d_in[38];

    // Workspace (~135 MB, known safe): R + 4x f32 regions + small stats.
    char* base = (char*)d_ws;
    auto alloc = [&](size_t nbytes){ char* p = base; base += (nbytes + 255) & ~(size_t)255; return p; };
    constexpr size_t SZ = (size_t)MTOT*CDIM*4;   // 25,690,112 B
    float* R  = (float*)alloc(SZ);
    float* A0 = (float*)alloc(SZ);
    float* A1 = (float*)alloc(SZ);
    float* B0 = (float*)alloc(SZ);
    float* B1 = (float*)alloc(SZ);
    // aliases (lifetimes annotated per stage below)
    bf16* A0b  = (bf16*)A0;                 // ln1 out [MTOT,256]   (first half of A0)
    bf16* qb   = A0b + (size_t)MTOT*CDIM;   // q softmax out        (second half of A0)
    bf16* attb = (bf16*)B0;                 // att out [MTOT,256]
    bf16* l2b  = (bf16*)A1;                 // ln2 out
    bf16* F    = (bf16*)B0;                 // fc1 out [MTOT,1024], spans B0..B1
    bf16* G    = (bf16*)A0;                 // dwconv out, spans A0..A1
    bf16* l3b  = (bf16*)B0;                 // ln3 out
    bf16* Qb   = (bf16*)A0;                 // qkv [MTOT,768], 38.5MB in A-span
    bf16* avb  = (bf16*)B0;                 // chan-attn out [MTOT,256]
    bf16* l4b  = (bf16*)A0;                 // ln4 out
    float* ctxf = (float*)alloc((size_t)BATCH*CDIM*CDIM*4);  // ctx^T f32 [8,256,256]
    float* lmax = (float*)alloc((size_t)BATCH*NCHUNK*CDIM*4);
    float* lsum = (float*)alloc((size_t)BATCH*NCHUNK*CDIM*4);
    float* gmax = (float*)alloc((size_t)BATCH*CDIM*4);
    float* ginv = (float*)alloc((size_t)BATCH*CDIM*4);
    float* lss  = (float*)alloc((size_t)BATCH*NCHUNK*512*4);
    float* invn = (float*)alloc((size_t)BATCH*512*4);
    float* attnb= (float*)alloc((size_t)BATCH*8*32*32*4);

    dim3 blk(256);
    constexpr int MB = MTOT/128;            // 196
    long long sA1 = (long long)NPOS*CDIM;   // batched att strides
    long long sB1 = (long long)CDIM*CDIM;

    // ---- Stage 1: EfficientAttention ----
    ln_kernel<256, float, bf16><<<MTOT, blk, 0, stream>>>(x, ln1g, ln1b, A0b);
    mfma_gemm<float><<<dim3(2,MB,1), blk, 0, stream>>>(A0b, eakw, eakb, nullptr, B0, MTOT, 256, 256, 0,0,0,0); // k f32
    mfma_gemm<float><<<dim3(2,MB,1), blk, 0, stream>>>(A0b, eaqw, eaqb, nullptr, B1, MTOT, 256, 256, 0,0,0,0); // q f32
    mfma_gemm<float><<<dim3(2,MB,1), blk, 0, stream>>>(A0b, eavw, eavb, nullptr, A1, MTOT, 256, 256, 0,0,0,0); // v f32
    rowsm_kernel<<<MTOT, blk, 0, stream>>>(B1, qb);                     // q softmax -> bf16
    colsm_p1<<<BATCH*NCHUNK, blk, 0, stream>>>(B0, lmax, lsum);         // k softmax (spatial)
    colsm_p2<<<BATCH, blk, 0, stream>>>(lmax, lsum, gmax, ginv);
    colsm_p3<<<MTOT, blk, 0, stream>>>(B0, gmax, ginv);
    gemm_tn_kernel<<<dim3(8,8,BATCH), blk, 0, stream>>>(A1, B0, ctxf);  // ctx^T[vc,kc] = sum_n v k
    mfma_gemm<bf16><<<dim3(2,25,BATCH), blk, 0, stream>>>(qb, ctxf, nullptr, nullptr, attb,
            NPOS, 256, 256, sA1, sB1, sA1, 0);                          // att = q @ ctx (overwrites dead k)
    mfma_gemm<float><<<dim3(2,MB,1), blk, 0, stream>>>(attb, earw, earb, x, R, MTOT, 256, 256, 0,0,0,0); // R = x + proj

    // ---- Stage 2: MixFFN #1 ----
    ln_kernel<256, float, bf16><<<MTOT, blk, 0, stream>>>(R, ln2g, ln2b, l2b);
    mfma_gemm<bf16><<<dim3(8,MB,1), blk, 0, stream>>>(l2b, m1w1, m1b1, nullptr, F, MTOT, 1024, 256, 0,0,0,0);
    dwconv_ln_gelu_kernel<<<MTOT, blk, 0, stream>>>(F, m1dww, m1dwb, m1lg, m1lb, G);   // B-span -> A-span
    mfma_gemm<float><<<dim3(2,MB,1), blk, 0, stream>>>(G, m1w2, m1b2, R, R, MTOT, 256, 1024, 0,0,0,0); // R += ffn

    // ---- Stage 3: ChannelAttention ----
    ln_kernel<256, float, bf16><<<MTOT, blk, 0, stream>>>(R, ln3g, ln3b, l3b);
    mfma_gemm<bf16><<<dim3(6,MB,1), blk, 0, stream>>>(l3b, caqkvw, nullptr, nullptr, Qb, MTOT, 768, 256, 0,0,0,0);
    ssq_p1<<<dim3(BATCH*NCHUNK,2), blk, 0, stream>>>(Qb, lss);
    ssq_p2<<<dim3(BATCH,2), blk, 0, stream>>>(lss, invn);
    chanattn_qk<<<BATCH*8, blk, 0, stream>>>(Qb, invn, catemp, attnb);
    chanattn_av<<<MTOT, blk, 0, stream>>>(Qb, attnb, avb);              // -> bf16 (l3b dead)
    mfma_gemm<float><<<dim3(2,MB,1), blk, 0, stream>>>(avb, capw, capb, R, R, MTOT, 256, 256, 0,0,0,0); // R += proj

    // ---- Stage 4: MixFFN #2 ----
    ln_kernel<256, float, bf16><<<MTOT, blk, 0, stream>>>(R, ln4g, ln4b, l4b);
    mfma_gemm<bf16><<<dim3(8,MB,1), blk, 0, stream>>>(l4b, m2w1, m2b1, nullptr, F, MTOT, 1024, 256, 0,0,0,0);
    dwconv_ln_gelu_kernel<<<MTOT, blk, 0, stream>>>(F, m2dww, m2dwb, m2lg, m2lb, G);
    mfma_gemm<float><<<dim3(2,MB,1), blk, 0, stream>>>(G, m2w2, m2b2, R, (float*)d_out, MTOT, 256, 1024, 0,0,0,0);
}

// Round 6
// 1067.712 us; speedup vs baseline: 2.7413x; 1.4491x over previous
//
#include <hip/hip_runtime.h>
#include <hip/hip_bf16.h>

typedef __hip_bfloat16 bf16;
typedef __attribute__((ext_vector_type(8))) short short8;
typedef __attribute__((ext_vector_type(4))) float floatx4;

#define DI __device__ __forceinline__

DI float ldf(const float* p, long long i){ return p[i]; }
DI float ldf(const bf16* p, long long i){ return __bfloat162float(p[i]); }
DI void stf(float* p, long long i, float v){ p[i] = v; }
DI void stf(bf16* p, long long i, float v){ p[i] = __float2bfloat16(v); }

DI unsigned short bfbits(float f){
    bf16 h = __float2bfloat16(f);
    return *reinterpret_cast<unsigned short*>(&h);
}
DI float bu(unsigned short u){
    union { unsigned int i; float f; } x; x.i = ((unsigned int)u) << 16; return x.f;
}

static constexpr int BATCH = 8;
static constexpr int HH = 56, WW = 56;
static constexpr int NPOS = HH * WW;        // 3136
static constexpr int CDIM = 256;
static constexpr int HIDD = 1024;
static constexpr int MTOT = BATCH * NPOS;   // 25088
static constexpr int NCHUNK = 49;           // 3136 / 64
static constexpr int LP = 40;               // LDS row pitch (shorts), 16B-aligned rows
static constexpr int TNS = 7;               // split-K factor for ctx TN gemm (448 rows each)

// ---------------- MFMA bf16 GEMM (NT: B[n,k]) ----------------
template<typename TC>
__global__ __launch_bounds__(256) void mfma_gemm(
    const bf16* __restrict__ A, const float* __restrict__ Bw,
    const float* __restrict__ bias, const float* __restrict__ addend,
    TC* __restrict__ C, int M, int N, int K,
    long long strA, long long strB, long long strC, long long strAdd)
{
    __shared__ short As[128*LP];
    __shared__ short Bs[128*LP];
    int tid = threadIdx.x;
    int bz = blockIdx.z;
    A  += (long long)bz * strA;
    Bw += (long long)bz * strB;
    C  += (long long)bz * strC;
    if (addend) addend += (long long)bz * strAdd;
    int n0 = blockIdx.x * 128, m0 = blockIdx.y * 128;
    int w = tid >> 6, lane = tid & 63, lm = lane & 15, quad = lane >> 4;
    int mw = (w >> 1) * 64, nw = (w & 1) * 64;

    floatx4 z = {0.f, 0.f, 0.f, 0.f};
    floatx4 acc[4][4];
    #pragma unroll
    for (int mi = 0; mi < 4; mi++)
        #pragma unroll
        for (int ni = 0; ni < 4; ni++) acc[mi][ni] = z;

    int bn = tid >> 1, bh = tid & 1;

    for (int k0 = 0; k0 < K; k0 += 32){
        #pragma unroll
        for (int cc = 0; cc < 2; cc++){
            int c = tid + cc*256;
            int row = c >> 2, col8 = (c & 3) * 8;
            int rg = m0 + row; if (rg > M-1) rg = M-1;
            uint4 v = *(const uint4*)(A + (long long)rg*K + k0 + col8);
            *(uint4*)&As[row*LP + col8] = v;
        }
        {
            const float* src = Bw + (long long)(n0 + bn)*K + k0 + bh*16;
            float4 f0 = *(const float4*)(src);
            float4 f1 = *(const float4*)(src + 4);
            float4 f2 = *(const float4*)(src + 8);
            float4 f3 = *(const float4*)(src + 12);
            union { uint4 u4; unsigned short us[8]; } p0, p1;
            p0.us[0]=bfbits(f0.x); p0.us[1]=bfbits(f0.y); p0.us[2]=bfbits(f0.z); p0.us[3]=bfbits(f0.w);
            p0.us[4]=bfbits(f1.x); p0.us[5]=bfbits(f1.y); p0.us[6]=bfbits(f1.z); p0.us[7]=bfbits(f1.w);
            p1.us[0]=bfbits(f2.x); p1.us[1]=bfbits(f2.y); p1.us[2]=bfbits(f2.z); p1.us[3]=bfbits(f2.w);
            p1.us[4]=bfbits(f3.x); p1.us[5]=bfbits(f3.y); p1.us[6]=bfbits(f3.z); p1.us[7]=bfbits(f3.w);
            *(uint4*)&Bs[bn*LP + bh*16]     = p0.u4;
            *(uint4*)&Bs[bn*LP + bh*16 + 8] = p1.u4;
        }
        __syncthreads();
        short8 af[4], bfr[4];
        #pragma unroll
        for (int mi = 0; mi < 4; mi++)
            af[mi] = *(const short8*)&As[(mw + mi*16 + lm)*LP + quad*8];
        #pragma unroll
        for (int ni = 0; ni < 4; ni++)
            bfr[ni] = *(const short8*)&Bs[(nw + ni*16 + lm)*LP + quad*8];
        #pragma unroll
        for (int mi = 0; mi < 4; mi++)
            #pragma unroll
            for (int ni = 0; ni < 4; ni++)
                acc[mi][ni] = __builtin_amdgcn_mfma_f32_16x16x32_bf16(af[mi], bfr[ni], acc[mi][ni], 0, 0, 0);
        __syncthreads();
    }

    #pragma unroll
    for (int ni = 0; ni < 4; ni++){
        int cg = n0 + nw + ni*16 + lm;
        float bv = bias ? bias[cg] : 0.f;
        #pragma unroll
        for (int mi = 0; mi < 4; mi++){
            #pragma unroll
            for (int r = 0; r < 4; r++){
                int rg = m0 + mw + mi*16 + quad*4 + r;
                if (rg < M){
                    long long idx = (long long)rg*N + cg;
                    float v = acc[mi][ni][r] + bv;
                    if (addend) v += addend[idx];
                    stf(C, idx, v);
                }
            }
        }
    }
}

// ---------------- MFMA bf16 TN GEMM: part[s][vc][kc] = sum_{n in split s} V[n,vc]*K[n,kc] ----------------
__global__ __launch_bounds__(256) void gemm_tn_mfma(const bf16* __restrict__ V, const bf16* __restrict__ Kb,
                                                    float* __restrict__ part){
    __shared__ short As[128*LP];   // [vc][n]
    __shared__ short Bs[128*LP];   // [kc][n]
    int tid = threadIdx.x;
    int bz = blockIdx.z;           // b*TNS + s
    int b = bz / TNS, s = bz % TNS;
    const bf16* Vb = V  + (long long)b*NPOS*CDIM;
    const bf16* Kc = Kb + (long long)b*NPOS*CDIM;
    int m0 = blockIdx.y * 128, n0 = blockIdx.x * 128;
    int w = tid >> 6, lane = tid & 63, lm = lane & 15, quad = lane >> 4;
    int mw = (w >> 1) * 64, nw = (w & 1) * 64;

    floatx4 z = {0.f,0.f,0.f,0.f};
    floatx4 acc[4][4];
    #pragma unroll
    for (int mi = 0; mi < 4; mi++)
        #pragma unroll
        for (int ni = 0; ni < 4; ni++) acc[mi][ni] = z;

    int r = tid & 31, cgrp = tid >> 5;   // 32 n-rows x 8 channel groups

    for (int step = 0; step < 448/32; step++){
        int nb = s*448 + step*32;
        #pragma unroll
        for (int cc = 0; cc < 2; cc++){
            int ch = cgrp*8 + cc*64;
            short8 va = *(const short8*)(Vb + (long long)(nb + r)*CDIM + m0 + ch);
            short8 ka = *(const short8*)(Kc + (long long)(nb + r)*CDIM + n0 + ch);
            #pragma unroll
            for (int i = 0; i < 8; i++){
                As[(ch+i)*LP + r] = va[i];
                Bs[(ch+i)*LP + r] = ka[i];
            }
        }
        __syncthreads();
        short8 af[4], bfr[4];
        #pragma unroll
        for (int mi = 0; mi < 4; mi++)
            af[mi] = *(const short8*)&As[(mw + mi*16 + lm)*LP + quad*8];
        #pragma unroll
        for (int ni = 0; ni < 4; ni++)
            bfr[ni] = *(const short8*)&Bs[(nw + ni*16 + lm)*LP + quad*8];
        #pragma unroll
        for (int mi = 0; mi < 4; mi++)
            #pragma unroll
            for (int ni = 0; ni < 4; ni++)
                acc[mi][ni] = __builtin_amdgcn_mfma_f32_16x16x32_bf16(af[mi], bfr[ni], acc[mi][ni], 0, 0, 0);
        __syncthreads();
    }

    float* pb = part + (long long)bz * CDIM * CDIM;
    #pragma unroll
    for (int ni = 0; ni < 4; ni++){
        int cg = n0 + nw + ni*16 + lm;
        #pragma unroll
        for (int mi = 0; mi < 4; mi++){
            #pragma unroll
            for (int rr = 0; rr < 4; rr++){
                int rg = m0 + mw + mi*16 + quad*4 + rr;
                pb[(long long)rg*CDIM + cg] = acc[mi][ni][rr];
            }
        }
    }
}

// ctxf[b][vc][kc] = sum_s part[b*TNS+s][vc][kc]
__global__ __launch_bounds__(256) void ctx_reduce(const float* __restrict__ part, float* __restrict__ ctxf){
    long long idx = (long long)blockIdx.x*256 + threadIdx.x;   // over 8*65536
    int b = (int)(idx >> 16);
    int rem = (int)(idx & 65535);
    float s = 0.f;
    #pragma unroll
    for (int sp = 0; sp < TNS; sp++)
        s += part[((long long)(b*TNS+sp) << 16) + rem];
    ctxf[idx] = s;
}

// ---------------- LayerNorm: one wave per row, float4 + shuffle reduce ----------------
DI void st4o(float* p, long long i, float a, float b, float c, float d){
    float4 v = make_float4(a,b,c,d); *(float4*)(p + i) = v;
}
DI void st4o(bf16* p, long long i, float a, float b, float c, float d){
    union { unsigned long long u; unsigned short us[4]; } pk;
    pk.us[0]=bfbits(a); pk.us[1]=bfbits(b); pk.us[2]=bfbits(c); pk.us[3]=bfbits(d);
    *(unsigned long long*)(p + i) = pk.u;
}
template<typename TOUT>
__global__ __launch_bounds__(256) void ln4_kernel(const float* __restrict__ x, const float* __restrict__ g,
                                                  const float* __restrict__ b, TOUT* __restrict__ y){
    int wv = threadIdx.x >> 6, lane = threadIdx.x & 63;
    long long row = (long long)blockIdx.x*4 + wv;
    float4 v = *(const float4*)(x + row*256 + lane*4);
    float s  = v.x + v.y + v.z + v.w;
    float ss = v.x*v.x + v.y*v.y + v.z*v.z + v.w*v.w;
    #pragma unroll
    for (int off = 32; off > 0; off >>= 1){
        s  += __shfl_down(s,  off);
        ss += __shfl_down(ss, off);
    }
    s = __shfl(s, 0); ss = __shfl(ss, 0);
    float mean = s * (1.f/256.f);
    float var  = ss * (1.f/256.f) - mean*mean;
    float inv  = rsqrtf(var + 1e-5f);
    float4 gv = *(const float4*)(g + lane*4);
    float4 bv = *(const float4*)(b + lane*4);
    st4o(y, row*256 + lane*4,
         (v.x-mean)*inv*gv.x + bv.x, (v.y-mean)*inv*gv.y + bv.y,
         (v.z-mean)*inv*gv.z + bv.z, (v.w-mean)*inv*gv.w + bv.w);
}

// ---------------- column softmax over N (for k), chunked two-phase ----------------
__global__ __launch_bounds__(256) void colsm_p1(const float* __restrict__ x, float* __restrict__ lmax, float* __restrict__ lsum){
    int b = blockIdx.x / NCHUNK, ch = blockIdx.x % NCHUNK;
    int c = threadIdx.x;
    const float* base = x + ((long long)b*NPOS + ch*64)*CDIM + c;
    float m = -1e30f;
    for (int r = 0; r < 64; r++) m = fmaxf(m, base[(long long)r*CDIM]);
    float s = 0.f;
    for (int r = 0; r < 64; r++) s += expf(base[(long long)r*CDIM] - m);
    lmax[(long long)blockIdx.x*CDIM + c] = m;
    lsum[(long long)blockIdx.x*CDIM + c] = s;
}
__global__ __launch_bounds__(256) void colsm_p2(const float* __restrict__ lmax, const float* __restrict__ lsum,
                                                float* __restrict__ gmax, float* __restrict__ ginv){
    int b = blockIdx.x; int c = threadIdx.x;
    float g = -1e30f;
    for (int ch = 0; ch < NCHUNK; ch++) g = fmaxf(g, lmax[((long long)b*NCHUNK+ch)*CDIM + c]);
    float s = 0.f;
    for (int ch = 0; ch < NCHUNK; ch++)
        s += lsum[((long long)b*NCHUNK+ch)*CDIM + c] * expf(lmax[((long long)b*NCHUNK+ch)*CDIM + c] - g);
    gmax[b*CDIM + c] = g; ginv[b*CDIM + c] = 1.f / s;
}
// k softmax finalize: f32 in -> bf16 out
__global__ __launch_bounds__(256) void colsm_p3(const float* __restrict__ x, bf16* __restrict__ y,
                                                const float* __restrict__ gmax, const float* __restrict__ ginv){
    long long idx = (long long)blockIdx.x*256 + threadIdx.x;
    int c = idx & (CDIM-1);
    int b = (int)(idx / ((long long)NPOS*CDIM));
    y[idx] = __float2bfloat16(expf(x[idx] - gmax[b*CDIM + c]) * ginv[b*CDIM + c]);
}

// ---------------- row softmax over C=256 (for q): f32 in, bf16 out ----------------
__global__ __launch_bounds__(256) void rowsm_kernel(const float* __restrict__ x, bf16* __restrict__ y){
    __shared__ float red[256];
    long long row = blockIdx.x;
    int tid = threadIdx.x;
    float v = x[row*256 + tid];
    red[tid] = v; __syncthreads();
    for (int st = 128; st > 0; st >>= 1){ if (tid < st) red[tid] = fmaxf(red[tid], red[tid+st]); __syncthreads(); }
    float m = red[0]; __syncthreads();
    float e = expf(v - m);
    red[tid] = e; __syncthreads();
    for (int st = 128; st > 0; st >>= 1){ if (tid < st) red[tid] += red[tid+st]; __syncthreads(); }
    y[row*256 + tid] = __float2bfloat16(e / red[0]);
}

// ---------------- fused dwconv3x3 + skip + LN + GELU, vectorized bf16x8 ----------------
// 2 positions per block; 128 threads/position, 8 channels/thread.
__global__ __launch_bounds__(256) void dwconv_ln_gelu_kernel(const bf16* __restrict__ f, const float* __restrict__ dw,
        const float* __restrict__ db, const float* __restrict__ lg, const float* __restrict__ lb, bf16* __restrict__ out){
    __shared__ float r1[2][128], r2[2][128];
    int tid = threadIdx.x;
    int half = tid >> 7, ct = tid & 127;
    int n = blockIdx.x*2 + half;
    int b = n / NPOS, hw = n % NPOS;
    int h = hw / WW, w = hw % WW;
    int c0 = ct * 8;
    const bf16* fb = f + (long long)b * NPOS * HIDD;

    // weights: 8 channels x 9 taps contiguous = 18 float4
    float wgt[72];
    {
        const float4* wp = (const float4*)(dw + c0*9);
        #pragma unroll
        for (int j = 0; j < 18; j++){
            float4 t = wp[j];
            wgt[j*4+0]=t.x; wgt[j*4+1]=t.y; wgt[j*4+2]=t.z; wgt[j*4+3]=t.w;
        }
    }
    float sv[8];
    {   // bias + skip (center row)
        float4 d0 = *(const float4*)(db + c0);
        float4 d1 = *(const float4*)(db + c0 + 4);
        union { uint4 u; unsigned short us[8]; } cv;
        cv.u = *(const uint4*)(fb + (long long)hw*HIDD + c0);
        sv[0]=d0.x+bu(cv.us[0]); sv[1]=d0.y+bu(cv.us[1]); sv[2]=d0.z+bu(cv.us[2]); sv[3]=d0.w+bu(cv.us[3]);
        sv[4]=d1.x+bu(cv.us[4]); sv[5]=d1.y+bu(cv.us[5]); sv[6]=d1.z+bu(cv.us[6]); sv[7]=d1.w+bu(cv.us[7]);
    }
    #pragma unroll
    for (int ky = 0; ky < 3; ky++){
        int hy = h + ky - 1;
        if (hy < 0 || hy >= HH) continue;
        #pragma unroll
        for (int kx = 0; kx < 3; kx++){
            int wx = w + kx - 1;
            if (wx < 0 || wx >= WW) continue;
            union { uint4 u; unsigned short us[8]; } tv;
            tv.u = *(const uint4*)(fb + (long long)(hy*WW + wx)*HIDD + c0);
            #pragma unroll
            for (int i = 0; i < 8; i++)
                sv[i] += bu(tv.us[i]) * wgt[i*9 + ky*3 + kx];
        }
    }
    float s = 0.f, ss = 0.f;
    #pragma unroll
    for (int i = 0; i < 8; i++){ s += sv[i]; ss += sv[i]*sv[i]; }
    r1[half][ct] = s; r2[half][ct] = ss; __syncthreads();
    for (int st = 64; st > 0; st >>= 1){
        if (ct < st){ r1[half][ct] += r1[half][ct+st]; r2[half][ct] += r2[half][ct+st]; }
        __syncthreads();
    }
    float mean = r1[half][0] * (1.f/HIDD);
    float var  = r2[half][0] * (1.f/HIDD) - mean*mean;
    float inv  = rsqrtf(var + 1e-5f);
    float4 g0 = *(const float4*)(lg + c0), g1 = *(const float4*)(lg + c0 + 4);
    float4 b0 = *(const float4*)(lb + c0), b1 = *(const float4*)(lb + c0 + 4);
    float gg[8] = {g0.x,g0.y,g0.z,g0.w,g1.x,g1.y,g1.z,g1.w};
    float bb[8] = {b0.x,b0.y,b0.z,b0.w,b1.x,b1.y,b1.z,b1.w};
    union { uint4 u; unsigned short us[8]; } ov;
    #pragma unroll
    for (int i = 0; i < 8; i++){
        float o = (sv[i]-mean)*inv*gg[i] + bb[i];
        o = 0.5f*o*(1.f + erff(o*0.70710678118654752f));
        ov.us[i] = bfbits(o);
    }
    *(uint4*)(out + (long long)n*HIDD + c0) = ov.u;
}

// ---------------- channel-attn: per-channel sum-sq over N, vectorized ----------------
__global__ __launch_bounds__(256) void ssq_p1(const bf16* __restrict__ qkv, float* __restrict__ lss){
    __shared__ float red[4][64][8];
    int b = blockIdx.x / NCHUNK, ch = blockIdx.x % NCHUNK;
    int tid = threadIdx.x;
    int col = (tid & 63) * 8;          // channels 0..511
    int rg = tid >> 6;                  // 4 row groups x 16 rows
    float s[8] = {0,0,0,0,0,0,0,0};
    for (int r = rg*16; r < rg*16 + 16; r++){
        long long row = (long long)(b*NPOS + ch*64 + r);
        union { uint4 u; unsigned short us[8]; } v;
        v.u = *(const uint4*)(qkv + row*768 + col);
        #pragma unroll
        for (int i = 0; i < 8; i++){ float f = bu(v.us[i]); s[i] += f*f; }
    }
    #pragma unroll
    for (int i = 0; i < 8; i++) red[rg][tid & 63][i] = s[i];
    __syncthreads();
    if (tid < 64){
        #pragma unroll
        for (int i = 0; i < 8; i++){
            float t = red[0][tid][i] + red[1][tid][i] + red[2][tid][i] + red[3][tid][i];
            lss[(long long)blockIdx.x*512 + tid*8 + i] = t;
        }
    }
}
__global__ __launch_bounds__(256) void ssq_p2(const float* __restrict__ lss, float* __restrict__ invn){
    int b = blockIdx.x; int c = blockIdx.y*256 + threadIdx.x;
    float s = 0.f;
    for (int ch = 0; ch < NCHUNK; ch++) s += lss[((long long)b*NCHUNK+ch)*512 + c];
    invn[b*512 + c] = 1.f / fmaxf(sqrtf(s), 1e-12f);
}

// ---------------- channel-attn QK: split partial dot products ----------------
__global__ __launch_bounds__(256) void chanattn_qk_part(const bf16* __restrict__ qkv, const float* __restrict__ invn,
                                                        float* __restrict__ part){
    __shared__ float qs[64][33];
    __shared__ float ks[64][33];
    int bz = blockIdx.x;               // (b*8+hh)*TNS + s
    int bh = bz / TNS, s = bz % TNS;
    int b = bh >> 3, hh = bh & 7;
    int tid = threadIdx.x;
    int d = tid >> 3, e0 = (tid & 7) * 4;
    float acc[4] = {0.f,0.f,0.f,0.f};
    for (int it = 0; it < 7; it++){
        int n0 = s*448 + it*64;
        #pragma unroll
        for (int i = 0; i < 8; i++){
            int e = tid + i*256; int r = e >> 5, c = e & 31;
            long long rowb = (long long)(b*NPOS + n0 + r) * 768;
            qs[r][c] = __bfloat162float(qkv[rowb + hh*32 + c])       * invn[b*512 + hh*32 + c];
            ks[r][c] = __bfloat162float(qkv[rowb + 256 + hh*32 + c]) * invn[b*512 + 256 + hh*32 + c];
        }
        __syncthreads();
        #pragma unroll 4
        for (int r = 0; r < 64; r++){
            float qv = qs[r][d];
            #pragma unroll
            for (int j = 0; j < 4; j++) acc[j] += qv * ks[r][e0+j];
        }
        __syncthreads();
    }
    #pragma unroll
    for (int j = 0; j < 4; j++)
        part[(long long)bz*1024 + d*32 + e0 + j] = acc[j];
}
__global__ __launch_bounds__(256) void chanattn_qk_fin(const float* __restrict__ part, const float* __restrict__ temp,
                                                       float* __restrict__ attn){
    __shared__ float att_s[32][33];
    int bh = blockIdx.x;               // b*8+hh
    int hh = bh & 7;
    int tid = threadIdx.x;
    int d = tid >> 3, e0 = (tid & 7) * 4;
    float t = temp[hh];
    #pragma unroll
    for (int j = 0; j < 4; j++){
        float s = 0.f;
        for (int sp = 0; sp < TNS; sp++)
            s += part[((long long)bh*TNS + sp)*1024 + d*32 + e0 + j];
        att_s[d][e0+j] = s * t;
    }
    __syncthreads();
    if (tid < 32){
        float m = -1e30f;
        for (int e = 0; e < 32; e++) m = fmaxf(m, att_s[tid][e]);
        float s = 0.f;
        for (int e = 0; e < 32; e++){ float ev = expf(att_s[tid][e] - m); att_s[tid][e] = ev; s += ev; }
        float inv = 1.f / s;
        for (int e = 0; e < 32; e++) att_s[tid][e] *= inv;
    }
    __syncthreads();
    #pragma unroll
    for (int j = 0; j < 4; j++)
        attn[(long long)bh*1024 + d*32 + e0 + j] = att_s[d][e0+j];
}

// ---------------- channel-attn AV ----------------
__global__ __launch_bounds__(256) void chanattn_av(const bf16* __restrict__ qkv, const float* __restrict__ attn,
                                                   bf16* __restrict__ out){
    __shared__ float vsh[256];
    long long n = blockIdx.x;
    int b = (int)(n / NPOS);
    int c = threadIdx.x;
    vsh[c] = __bfloat162float(qkv[n*768 + 512 + c]);
    __syncthreads();
    int hh = c >> 5;
    const float* arow = attn + ((long long)(b*8+hh)*32 + (c & 31))*32;
    float s = 0.f;
    #pragma unroll
    for (int e = 0; e < 32; e++) s += arow[e] * vsh[hh*32 + e];
    out[n*256 + c] = __float2bfloat16(s);
}

// ---------------- orchestration ----------------
extern "C" void kernel_launch(void* const* d_in, const int* in_sizes, int n_in,
                              void* d_out, int out_size, void* d_ws, size_t ws_size,
                              hipStream_t stream){
    const float* x     = (const float*)d_in[0];
    const float* ln1g  = (const float*)d_in[3];
    const float* ln1b  = (const float*)d_in[4];
    const float* eakw  = (const float*)d_in[5];
    const float* eakb  = (const float*)d_in[6];
    const float* eaqw  = (const float*)d_in[7];
    const float* eaqb  = (const float*)d_in[8];
    const float* eavw  = (const float*)d_in[9];
    const float* eavb  = (const float*)d_in[10];
    const float* earw  = (const float*)d_in[11];
    const float* earb  = (const float*)d_in[12];
    const float* ln2g  = (const float*)d_in[13];
    const float* ln2b  = (const float*)d_in[14];
    const float* m1w1  = (const float*)d_in[15];
    const float* m1b1  = (const float*)d_in[16];
    const float* m1dww = (const float*)d_in[17];
    const float* m1dwb = (const float*)d_in[18];
    const float* m1lg  = (const float*)d_in[19];
    const float* m1lb  = (const float*)d_in[20];
    const float* m1w2  = (const float*)d_in[21];
    const float* m1b2  = (const float*)d_in[22];
    const float* ln3g  = (const float*)d_in[23];
    const float* ln3b  = (const float*)d_in[24];
    const float* catemp= (const float*)d_in[25];
    const float* caqkvw= (const float*)d_in[26];
    const float* capw  = (const float*)d_in[27];
    const float* capb  = (const float*)d_in[28];
    const float* ln4g  = (const float*)d_in[29];
    const float* ln4b  = (const float*)d_in[30];
    const float* m2w1  = (const float*)d_in[31];
    const float* m2b1  = (const float*)d_in[32];
    const float* m2dww = (const float*)d_in[33];
    const float* m2dwb = (const float*)d_in[34];
    const float* m2lg  = (const float*)d_in[35];
    const float* m2lb  = (const float*)d_in[36];
    const float* m2w2  = (const float*)d_in[37];
    const float* m2b2  = (const float*)d_in[38];

    // Workspace ~150 MB (known safe < 209 MB).
    char* base = (char*)d_ws;
    auto alloc = [&](size_t nbytes){ char* p = base; base += (nbytes + 255) & ~(size_t)255; return p; };
    constexpr size_t SZ = (size_t)MTOT*CDIM*4;
    float* R  = (float*)alloc(SZ);
    float* A0 = (float*)alloc(SZ);
    float* A1 = (float*)alloc(SZ);
    float* B0 = (float*)alloc(SZ);
    float* B1 = (float*)alloc(SZ);
    // aliases (stage lifetimes):
    bf16* A0b  = (bf16*)A0;                 // s1: ln1 out (first half A0)
    bf16* qb   = A0b + (size_t)MTOT*CDIM;   // s1: q softmax out (second half A0)
    bf16* vb   = (bf16*)A1;                 // s1: v bf16
    bf16* kb   = (bf16*)B1;                 // s1: k softmax bf16 (B1 dead after rowsm)
    bf16* attb = (bf16*)B0;                 // s1: att out (B0's f32 k dead)
    bf16* l2b  = (bf16*)A1;                 // s2: ln2 out
    bf16* F    = (bf16*)B0;                 // s2/s4: fc1 out, spans B0..B1
    bf16* G    = (bf16*)A0;                 // s2/s4: dwconv out, spans A0..A1
    bf16* l3b  = (bf16*)B0;                 // s3: ln3 out
    bf16* Qb   = (bf16*)A0;                 // s3: qkv, spans A0..A1 (38.5 MB)
    bf16* avb  = (bf16*)B0;                 // s3: chan-attn out
    bf16* l4b  = (bf16*)A0;                 // s4: ln4 out
    float* ctxf = (float*)alloc((size_t)BATCH*CDIM*CDIM*4);
    float* lmax = (float*)alloc((size_t)BATCH*NCHUNK*CDIM*4);
    float* lsum = (float*)alloc((size_t)BATCH*NCHUNK*CDIM*4);
    float* gmax = (float*)alloc((size_t)BATCH*CDIM*4);
    float* ginv = (float*)alloc((size_t)BATCH*CDIM*4);
    float* lss  = (float*)alloc((size_t)BATCH*NCHUNK*512*4);
    float* invn = (float*)alloc((size_t)BATCH*512*4);
    float* attnb= (float*)alloc((size_t)BATCH*8*32*32*4);
    float* ptn  = (float*)alloc((size_t)BATCH*TNS*CDIM*CDIM*4);  // 14.7 MB
    float* pqk  = (float*)alloc((size_t)BATCH*8*TNS*1024*4);     // 1.8 MB

    dim3 blk(256);
    constexpr int MB = MTOT/128;            // 196
    long long sA1 = (long long)NPOS*CDIM;
    long long sB1 = (long long)CDIM*CDIM;

    // ---- Stage 1: EfficientAttention ----
    ln4_kernel<bf16><<<MTOT/4, blk, 0, stream>>>(x, ln1g, ln1b, A0b);
    mfma_gemm<float><<<dim3(2,MB,1), blk, 0, stream>>>(A0b, eakw, eakb, nullptr, B0, MTOT, 256, 256, 0,0,0,0); // k f32
    mfma_gemm<float><<<dim3(2,MB,1), blk, 0, stream>>>(A0b, eaqw, eaqb, nullptr, B1, MTOT, 256, 256, 0,0,0,0); // q f32
    mfma_gemm<bf16><<<dim3(2,MB,1), blk, 0, stream>>>(A0b, eavw, eavb, nullptr, vb, MTOT, 256, 256, 0,0,0,0);  // v bf16
    rowsm_kernel<<<MTOT, blk, 0, stream>>>(B1, qb);                     // q softmax -> bf16 (B1 now dead)
    colsm_p1<<<BATCH*NCHUNK, blk, 0, stream>>>(B0, lmax, lsum);
    colsm_p2<<<BATCH, blk, 0, stream>>>(lmax, lsum, gmax, ginv);
    colsm_p3<<<MTOT, blk, 0, stream>>>(B0, kb, gmax, ginv);             // k softmax -> bf16 in B1
    gemm_tn_mfma<<<dim3(2,2,BATCH*TNS), blk, 0, stream>>>(vb, kb, ptn); // ctx^T partials
    ctx_reduce<<<(BATCH*65536)/256, blk, 0, stream>>>(ptn, ctxf);
    mfma_gemm<bf16><<<dim3(2,25,BATCH), blk, 0, stream>>>(qb, ctxf, nullptr, nullptr, attb,
            NPOS, 256, 256, sA1, sB1, sA1, 0);                          // att = q @ ctx
    mfma_gemm<float><<<dim3(2,MB,1), blk, 0, stream>>>(attb, earw, earb, x, R, MTOT, 256, 256, 0,0,0,0); // R = x + proj

    // ---- Stage 2: MixFFN #1 ----
    ln4_kernel<bf16><<<MTOT/4, blk, 0, stream>>>(R, ln2g, ln2b, l2b);
    mfma_gemm<bf16><<<dim3(8,MB,1), blk, 0, stream>>>(l2b, m1w1, m1b1, nullptr, F, MTOT, 1024, 256, 0,0,0,0);
    dwconv_ln_gelu_kernel<<<MTOT/2, blk, 0, stream>>>(F, m1dww, m1dwb, m1lg, m1lb, G);
    mfma_gemm<float><<<dim3(2,MB,1), blk, 0, stream>>>(G, m1w2, m1b2, R, R, MTOT, 256, 1024, 0,0,0,0);

    // ---- Stage 3: ChannelAttention ----
    ln4_kernel<bf16><<<MTOT/4, blk, 0, stream>>>(R, ln3g, ln3b, l3b);
    mfma_gemm<bf16><<<dim3(6,MB,1), blk, 0, stream>>>(l3b, caqkvw, nullptr, nullptr, Qb, MTOT, 768, 256, 0,0,0,0);
    ssq_p1<<<BATCH*NCHUNK, blk, 0, stream>>>(Qb, lss);
    ssq_p2<<<dim3(BATCH,2), blk, 0, stream>>>(lss, invn);
    chanattn_qk_part<<<BATCH*8*TNS, blk, 0, stream>>>(Qb, invn, pqk);
    chanattn_qk_fin<<<BATCH*8, blk, 0, stream>>>(pqk, catemp, attnb);
    chanattn_av<<<MTOT, blk, 0, stream>>>(Qb, attnb, avb);
    mfma_gemm<float><<<dim3(2,MB,1), blk, 0, stream>>>(avb, capw, capb, R, R, MTOT, 256, 256, 0,0,0,0);

    // ---- Stage 4: MixFFN #2 ----
    ln4_kernel<bf16><<<MTOT/4, blk, 0, stream>>>(R, ln4g, ln4b, l4b);
    mfma_gemm<bf16><<<dim3(8,MB,1), blk, 0, stream>>>(l4b, m2w1, m2b1, nullptr, F, MTOT, 1024, 256, 0,0,0,0);
    dwconv_ln_gelu_kernel<<<MTOT/2, blk, 0, stream>>>(F, m2dww, m2dwb, m2lg, m2lb, G);
    mfma_gemm<float><<<dim3(2,MB,1), blk, 0, stream>>>(G, m2w2, m2b2, R, (float*)d_out, MTOT, 256, 1024, 0,0,0,0);
}

// Round 7
// 957.464 us; speedup vs baseline: 3.0569x; 1.1151x over previous
//
#include <hip/hip_runtime.h>
#include <hip/hip_bf16.h>

typedef __hip_bfloat16 bf16;
typedef __attribute__((ext_vector_type(8))) short short8;
typedef __attribute__((ext_vector_type(4))) float floatx4;

#define DI __device__ __forceinline__

DI float ldf(const float* p, long long i){ return p[i]; }
DI float ldf(const bf16* p, long long i){ return __bfloat162float(p[i]); }
DI void stf(float* p, long long i, float v){ p[i] = v; }
DI void stf(bf16* p, long long i, float v){ p[i] = __float2bfloat16(v); }

DI unsigned short bfbits(float f){
    bf16 h = __float2bfloat16(f);
    return *reinterpret_cast<unsigned short*>(&h);
}
DI float bu(unsigned short u){
    union { unsigned int i; float f; } x; x.i = ((unsigned int)u) << 16; return x.f;
}

static constexpr int BATCH = 8;
static constexpr int HH = 56, WW = 56;
static constexpr int NPOS = HH * WW;        // 3136
static constexpr int CDIM = 256;
static constexpr int HIDD = 1024;
static constexpr int MTOT = BATCH * NPOS;   // 25088
static constexpr int NCHUNK = 49;           // 3136 / 64
static constexpr int LP = 40;               // LDS row pitch (shorts)
static constexpr int TNS = 7;               // split-K for ctx TN gemm

// ---------------- weight f32 -> bf16 pre-convert (10 matrices, one launch) ----------------
struct WArgs {
    const float* src[10];
    bf16* dst[10];
    int n[10];
};
__global__ __launch_bounds__(256) void wcvt_kernel(WArgs a){
    int wid = blockIdx.y;
    int i = (blockIdx.x*256 + threadIdx.x) * 8;
    if (i >= a.n[wid]) return;
    const float* s = a.src[wid] + i;
    float4 f0 = *(const float4*)(s);
    float4 f1 = *(const float4*)(s + 4);
    union { uint4 u; unsigned short us[8]; } p;
    p.us[0]=bfbits(f0.x); p.us[1]=bfbits(f0.y); p.us[2]=bfbits(f0.z); p.us[3]=bfbits(f0.w);
    p.us[4]=bfbits(f1.x); p.us[5]=bfbits(f1.y); p.us[6]=bfbits(f1.z); p.us[7]=bfbits(f1.w);
    *(uint4*)(a.dst[wid] + i) = p.u;
}

// dwconv weight transpose: t[tap*1024+c] = w[c*9+tap]  (f32, 9216 elems each)
__global__ __launch_bounds__(256) void wtrans_kernel(const float* __restrict__ w1, const float* __restrict__ w2,
                                                     float* __restrict__ t1, float* __restrict__ t2){
    int i = blockIdx.x*256 + threadIdx.x;   // 0..9215
    const float* w = blockIdx.y ? w2 : w1;
    float* t = blockIdx.y ? t2 : t1;
    int tap = i >> 10, c = i & 1023;
    t[i] = w[c*9 + tap];
}

// ---------------- MFMA bf16 GEMM (NT: B[n,k], both bf16) ----------------
template<typename TC>
__global__ __launch_bounds__(256) void mfma_gemm(
    const bf16* __restrict__ A, const bf16* __restrict__ Bw,
    const float* __restrict__ bias, const float* __restrict__ addend,
    TC* __restrict__ C, int M, int N, int K,
    long long strA, long long strB, long long strC, long long strAdd)
{
    __shared__ short As[128*LP];
    __shared__ short Bs[128*LP];
    int tid = threadIdx.x;
    int bz = blockIdx.z;
    A  += (long long)bz * strA;
    Bw += (long long)bz * strB;
    C  += (long long)bz * strC;
    if (addend) addend += (long long)bz * strAdd;
    int n0 = blockIdx.x * 128, m0 = blockIdx.y * 128;
    int w = tid >> 6, lane = tid & 63, lm = lane & 15, quad = lane >> 4;
    int mw = (w >> 1) * 64, nw = (w & 1) * 64;

    floatx4 z = {0.f, 0.f, 0.f, 0.f};
    floatx4 acc[4][4];
    #pragma unroll
    for (int mi = 0; mi < 4; mi++)
        #pragma unroll
        for (int ni = 0; ni < 4; ni++) acc[mi][ni] = z;

    for (int k0 = 0; k0 < K; k0 += 32){
        #pragma unroll
        for (int cc = 0; cc < 2; cc++){
            int c = tid + cc*256;
            int row = c >> 2, col8 = (c & 3) * 8;
            int rg = m0 + row; if (rg > M-1) rg = M-1;
            *(uint4*)&As[row*LP + col8] = *(const uint4*)(A + (long long)rg*K + k0 + col8);
            *(uint4*)&Bs[row*LP + col8] = *(const uint4*)(Bw + (long long)(n0+row)*K + k0 + col8);
        }
        __syncthreads();
        short8 af[4], bfr[4];
        #pragma unroll
        for (int mi = 0; mi < 4; mi++)
            af[mi] = *(const short8*)&As[(mw + mi*16 + lm)*LP + quad*8];
        #pragma unroll
        for (int ni = 0; ni < 4; ni++)
            bfr[ni] = *(const short8*)&Bs[(nw + ni*16 + lm)*LP + quad*8];
        #pragma unroll
        for (int mi = 0; mi < 4; mi++)
            #pragma unroll
            for (int ni = 0; ni < 4; ni++)
                acc[mi][ni] = __builtin_amdgcn_mfma_f32_16x16x32_bf16(af[mi], bfr[ni], acc[mi][ni], 0, 0, 0);
        __syncthreads();
    }

    #pragma unroll
    for (int ni = 0; ni < 4; ni++){
        int cg = n0 + nw + ni*16 + lm;
        float bv = bias ? bias[cg] : 0.f;
        #pragma unroll
        for (int mi = 0; mi < 4; mi++){
            #pragma unroll
            for (int r = 0; r < 4; r++){
                int rg = m0 + mw + mi*16 + quad*4 + r;
                if (rg < M){
                    long long idx = (long long)rg*N + cg;
                    float v = acc[mi][ni][r] + bv;
                    if (addend) v += addend[idx];
                    stf(C, idx, v);
                }
            }
        }
    }
}

// ---------------- MFMA bf16 TN GEMM: part[s][vc][kc] = sum_{n in split s} V[n,vc]*K[n,kc] ----------------
__global__ __launch_bounds__(256) void gemm_tn_mfma(const bf16* __restrict__ V, const bf16* __restrict__ Kb,
                                                    float* __restrict__ part){
    __shared__ short As[128*LP];
    __shared__ short Bs[128*LP];
    int tid = threadIdx.x;
    int bz = blockIdx.z;           // b*TNS + s
    int b = bz / TNS, s = bz % TNS;
    const bf16* Vb = V  + (long long)b*NPOS*CDIM;
    const bf16* Kc = Kb + (long long)b*NPOS*CDIM;
    int m0 = blockIdx.y * 128, n0 = blockIdx.x * 128;
    int w = tid >> 6, lane = tid & 63, lm = lane & 15, quad = lane >> 4;
    int mw = (w >> 1) * 64, nw = (w & 1) * 64;

    floatx4 z = {0.f,0.f,0.f,0.f};
    floatx4 acc[4][4];
    #pragma unroll
    for (int mi = 0; mi < 4; mi++)
        #pragma unroll
        for (int ni = 0; ni < 4; ni++) acc[mi][ni] = z;

    int r = tid & 31, cgrp = tid >> 5;

    for (int step = 0; step < 448/32; step++){
        int nb = s*448 + step*32;
        #pragma unroll
        for (int cc = 0; cc < 2; cc++){
            int ch = cgrp*8 + cc*64;
            short8 va = *(const short8*)(Vb + (long long)(nb + r)*CDIM + m0 + ch);
            short8 ka = *(const short8*)(Kc + (long long)(nb + r)*CDIM + n0 + ch);
            #pragma unroll
            for (int i = 0; i < 8; i++){
                As[(ch+i)*LP + r] = va[i];
                Bs[(ch+i)*LP + r] = ka[i];
            }
        }
        __syncthreads();
        short8 af[4], bfr[4];
        #pragma unroll
        for (int mi = 0; mi < 4; mi++)
            af[mi] = *(const short8*)&As[(mw + mi*16 + lm)*LP + quad*8];
        #pragma unroll
        for (int ni = 0; ni < 4; ni++)
            bfr[ni] = *(const short8*)&Bs[(nw + ni*16 + lm)*LP + quad*8];
        #pragma unroll
        for (int mi = 0; mi < 4; mi++)
            #pragma unroll
            for (int ni = 0; ni < 4; ni++)
                acc[mi][ni] = __builtin_amdgcn_mfma_f32_16x16x32_bf16(af[mi], bfr[ni], acc[mi][ni], 0, 0, 0);
        __syncthreads();
    }

    float* pb = part + (long long)bz * CDIM * CDIM;
    #pragma unroll
    for (int ni = 0; ni < 4; ni++){
        int cg = n0 + nw + ni*16 + lm;
        #pragma unroll
        for (int mi = 0; mi < 4; mi++){
            #pragma unroll
            for (int rr = 0; rr < 4; rr++){
                int rg = m0 + mw + mi*16 + quad*4 + rr;
                pb[(long long)rg*CDIM + cg] = acc[mi][ni][rr];
            }
        }
    }
}

// ctx[b][vc][kc] = sum_s part -> bf16
__global__ __launch_bounds__(256) void ctx_reduce(const float* __restrict__ part, bf16* __restrict__ ctxb){
    long long idx = (long long)blockIdx.x*256 + threadIdx.x;   // over 8*65536
    int b = (int)(idx >> 16);
    int rem = (int)(idx & 65535);
    float s = 0.f;
    #pragma unroll
    for (int sp = 0; sp < TNS; sp++)
        s += part[((long long)(b*TNS+sp) << 16) + rem];
    ctxb[idx] = __float2bfloat16(s);
}

// ---------------- LayerNorm: one wave per row ----------------
DI void st4o(float* p, long long i, float a, float b, float c, float d){
    float4 v = make_float4(a,b,c,d); *(float4*)(p + i) = v;
}
DI void st4o(bf16* p, long long i, float a, float b, float c, float d){
    union { unsigned long long u; unsigned short us[4]; } pk;
    pk.us[0]=bfbits(a); pk.us[1]=bfbits(b); pk.us[2]=bfbits(c); pk.us[3]=bfbits(d);
    *(unsigned long long*)(p + i) = pk.u;
}
template<typename TOUT>
__global__ __launch_bounds__(256) void ln4_kernel(const float* __restrict__ x, const float* __restrict__ g,
                                                  const float* __restrict__ b, TOUT* __restrict__ y){
    int wv = threadIdx.x >> 6, lane = threadIdx.x & 63;
    long long row = (long long)blockIdx.x*4 + wv;
    float4 v = *(const float4*)(x + row*256 + lane*4);
    float s  = v.x + v.y + v.z + v.w;
    float ss = v.x*v.x + v.y*v.y + v.z*v.z + v.w*v.w;
    #pragma unroll
    for (int off = 32; off > 0; off >>= 1){
        s  += __shfl_down(s,  off);
        ss += __shfl_down(ss, off);
    }
    s = __shfl(s, 0); ss = __shfl(ss, 0);
    float mean = s * (1.f/256.f);
    float var  = ss * (1.f/256.f) - mean*mean;
    float inv  = rsqrtf(var + 1e-5f);
    float4 gv = *(const float4*)(g + lane*4);
    float4 bv = *(const float4*)(b + lane*4);
    st4o(y, row*256 + lane*4,
         (v.x-mean)*inv*gv.x + bv.x, (v.y-mean)*inv*gv.y + bv.y,
         (v.z-mean)*inv*gv.z + bv.z, (v.w-mean)*inv*gv.w + bv.w);
}

// ---------------- column softmax over N (for k) ----------------
__global__ __launch_bounds__(256) void colsm_p1(const float* __restrict__ x, float* __restrict__ lmax, float* __restrict__ lsum){
    int b = blockIdx.x / NCHUNK, ch = blockIdx.x % NCHUNK;
    int c = threadIdx.x;
    const float* base = x + ((long long)b*NPOS + ch*64)*CDIM + c;
    float m = -1e30f;
    for (int r = 0; r < 64; r++) m = fmaxf(m, base[(long long)r*CDIM]);
    float s = 0.f;
    for (int r = 0; r < 64; r++) s += expf(base[(long long)r*CDIM] - m);
    lmax[(long long)blockIdx.x*CDIM + c] = m;
    lsum[(long long)blockIdx.x*CDIM + c] = s;
}
__global__ __launch_bounds__(256) void colsm_p2(const float* __restrict__ lmax, const float* __restrict__ lsum,
                                                float* __restrict__ gmax, float* __restrict__ ginv){
    int b = blockIdx.x; int c = threadIdx.x;
    float g = -1e30f;
    for (int ch = 0; ch < NCHUNK; ch++) g = fmaxf(g, lmax[((long long)b*NCHUNK+ch)*CDIM + c]);
    float s = 0.f;
    for (int ch = 0; ch < NCHUNK; ch++)
        s += lsum[((long long)b*NCHUNK+ch)*CDIM + c] * expf(lmax[((long long)b*NCHUNK+ch)*CDIM + c] - g);
    gmax[b*CDIM + c] = g; ginv[b*CDIM + c] = 1.f / s;
}
__global__ __launch_bounds__(256) void colsm_p3(const float* __restrict__ x, bf16* __restrict__ y,
                                                const float* __restrict__ gmax, const float* __restrict__ ginv){
    long long idx = (long long)blockIdx.x*256 + threadIdx.x;
    int c = idx & (CDIM-1);
    int b = (int)(idx / ((long long)NPOS*CDIM));
    y[idx] = __float2bfloat16(expf(x[idx] - gmax[b*CDIM + c]) * ginv[b*CDIM + c]);
}

// ---------------- row softmax over C=256 (for q) ----------------
__global__ __launch_bounds__(256) void rowsm_kernel(const float* __restrict__ x, bf16* __restrict__ y){
    __shared__ float red[256];
    long long row = blockIdx.x;
    int tid = threadIdx.x;
    float v = x[row*256 + tid];
    red[tid] = v; __syncthreads();
    for (int st = 128; st > 0; st >>= 1){ if (tid < st) red[tid] = fmaxf(red[tid], red[tid+st]); __syncthreads(); }
    float m = red[0]; __syncthreads();
    float e = expf(v - m);
    red[tid] = e; __syncthreads();
    for (int st = 128; st > 0; st >>= 1){ if (tid < st) red[tid] += red[tid+st]; __syncthreads(); }
    y[row*256 + tid] = __float2bfloat16(e / red[0]);
}

// ---------------- fused dwconv3x3 + skip + LN + GELU, LDS-tiled (4 positions/block) ----------------
// wT: transposed weights [tap][1024] f32. Block: (b,h,w0..w0+3). 256 thr:
// ph=tid>>7 -> positions {2ph, 2ph+1}; ct=tid&127 -> channels ct*8..ct*8+7.
__global__ __launch_bounds__(256) void dwconv_ln_gelu_kernel(const bf16* __restrict__ f, const float* __restrict__ wT,
        const float* __restrict__ db, const float* __restrict__ lg, const float* __restrict__ lb, bf16* __restrict__ out){
    __shared__ short Ls[18*1024];            // [row0..2][col0..5][1024ch]
    __shared__ float r1[2][2][128], r2[2][2][128];
    int tid = threadIdx.x;
    int blk = blockIdx.x;
    int b = blk / 784;                       // 784 = 56*14
    int rem = blk % 784;
    int h = rem / 14, w0 = (rem % 14) * 4;
    const bf16* fb = f + (long long)b * NPOS * HIDD;

    // ---- stage 3 rows x 6 cols x 1024 ch into LDS (zero-fill borders) ----
    #pragma unroll
    for (int j = 0; j < 9; j++){
        int idx = j*256 + tid;               // 0..2303
        int rc = idx >> 7, chunk = idx & 127;
        int row = rc / 6, col = rc % 6;
        int hy = h - 1 + row, wx = w0 - 1 + col;
        uint4 v = {0,0,0,0};
        if (hy >= 0 && hy < HH && wx >= 0 && wx < WW)
            v = *(const uint4*)(fb + (long long)(hy*WW + wx)*HIDD + chunk*8);
        *(uint4*)&Ls[rc*1024 + chunk*8] = v;
    }
    __syncthreads();

    int ph = tid >> 7, ct = tid & 127;
    int c0 = ct * 8;
    float sv[2][8];
    {
        float4 d0 = *(const float4*)(db + c0);
        float4 d1 = *(const float4*)(db + c0 + 4);
        #pragma unroll
        for (int pp = 0; pp < 2; pp++){
            sv[pp][0]=d0.x; sv[pp][1]=d0.y; sv[pp][2]=d0.z; sv[pp][3]=d0.w;
            sv[pp][4]=d1.x; sv[pp][5]=d1.y; sv[pp][6]=d1.z; sv[pp][7]=d1.w;
        }
    }
    #pragma unroll
    for (int tap = 0; tap < 9; tap++){
        int ky = tap / 3, kx = tap % 3;
        float4 w0v = *(const float4*)(wT + tap*1024 + c0);
        float4 w1v = *(const float4*)(wT + tap*1024 + c0 + 4);
        float wv[8] = {w0v.x,w0v.y,w0v.z,w0v.w,w1v.x,w1v.y,w1v.z,w1v.w};
        #pragma unroll
        for (int pp = 0; pp < 2; pp++){
            int pos_local = 2*ph + pp;
            short8 val = *(const short8*)&Ls[(ky*6 + pos_local + kx)*1024 + c0];
            #pragma unroll
            for (int i = 0; i < 8; i++){
                float fv = bu((unsigned short)val[i]);
                sv[pp][i] += fv * wv[i];
                if (tap == 4) sv[pp][i] += fv;   // skip connection (center tap)
            }
        }
    }
    // ---- LN reduction per position ----
    #pragma unroll
    for (int pp = 0; pp < 2; pp++){
        float s = 0.f, ss = 0.f;
        #pragma unroll
        for (int i = 0; i < 8; i++){ s += sv[pp][i]; ss += sv[pp][i]*sv[pp][i]; }
        r1[ph][pp][ct] = s; r2[ph][pp][ct] = ss;
    }
    __syncthreads();
    for (int st = 64; st > 0; st >>= 1){
        if (ct < st){
            #pragma unroll
            for (int pp = 0; pp < 2; pp++){
                r1[ph][pp][ct] += r1[ph][pp][ct+st];
                r2[ph][pp][ct] += r2[ph][pp][ct+st];
            }
        }
        __syncthreads();
    }
    float4 g0 = *(const float4*)(lg + c0), g1 = *(const float4*)(lg + c0 + 4);
    float4 b0 = *(const float4*)(lb + c0), b1 = *(const float4*)(lb + c0 + 4);
    float gg[8] = {g0.x,g0.y,g0.z,g0.w,g1.x,g1.y,g1.z,g1.w};
    float bb[8] = {b0.x,b0.y,b0.z,b0.w,b1.x,b1.y,b1.z,b1.w};
    #pragma unroll
    for (int pp = 0; pp < 2; pp++){
        int pos_local = 2*ph + pp;
        long long n = (long long)b*NPOS + h*WW + (w0 + pos_local);
        float mean = r1[ph][pp][0] * (1.f/HIDD);
        float var  = r2[ph][pp][0] * (1.f/HIDD) - mean*mean;
        float inv  = rsqrtf(var + 1e-5f);
        union { uint4 u; unsigned short us[8]; } ov;
        #pragma unroll
        for (int i = 0; i < 8; i++){
            float o = (sv[pp][i]-mean)*inv*gg[i] + bb[i];
            o = 0.5f*o*(1.f + erff(o*0.70710678118654752f));
            ov.us[i] = bfbits(o);
        }
        *(uint4*)(out + n*HIDD + c0) = ov.u;
    }
}

// ---------------- channel-attn: per-channel sum-sq over N ----------------
__global__ __launch_bounds__(256) void ssq_p1(const bf16* __restrict__ qkv, float* __restrict__ lss){
    __shared__ float red[4][64][8];
    int b = blockIdx.x / NCHUNK, ch = blockIdx.x % NCHUNK;
    int tid = threadIdx.x;
    int col = (tid & 63) * 8;
    int rg = tid >> 6;
    float s[8] = {0,0,0,0,0,0,0,0};
    for (int r = rg*16; r < rg*16 + 16; r++){
        long long row = (long long)(b*NPOS + ch*64 + r);
        union { uint4 u; unsigned short us[8]; } v;
        v.u = *(const uint4*)(qkv + row*768 + col);
        #pragma unroll
        for (int i = 0; i < 8; i++){ float f = bu(v.us[i]); s[i] += f*f; }
    }
    #pragma unroll
    for (int i = 0; i < 8; i++) red[rg][tid & 63][i] = s[i];
    __syncthreads();
    if (tid < 64){
        #pragma unroll
        for (int i = 0; i < 8; i++){
            float t = red[0][tid][i] + red[1][tid][i] + red[2][tid][i] + red[3][tid][i];
            lss[(long long)blockIdx.x*512 + tid*8 + i] = t;
        }
    }
}
__global__ __launch_bounds__(256) void ssq_p2(const float* __restrict__ lss, float* __restrict__ invn){
    int b = blockIdx.x; int c = blockIdx.y*256 + threadIdx.x;
    float s = 0.f;
    for (int ch = 0; ch < NCHUNK; ch++) s += lss[((long long)b*NCHUNK+ch)*512 + c];
    invn[b*512 + c] = 1.f / fmaxf(sqrtf(s), 1e-12f);
}

// ---------------- channel-attn QK partials ----------------
__global__ __launch_bounds__(256) void chanattn_qk_part(const bf16* __restrict__ qkv, const float* __restrict__ invn,
                                                        float* __restrict__ part){
    __shared__ float qs[64][33];
    __shared__ float ks[64][33];
    int bz = blockIdx.x;               // (b*8+hh)*TNS + s
    int bh = bz / TNS, s = bz % TNS;
    int b = bh >> 3, hh = bh & 7;
    int tid = threadIdx.x;
    int d = tid >> 3, e0 = (tid & 7) * 4;
    float acc[4] = {0.f,0.f,0.f,0.f};
    for (int it = 0; it < 7; it++){
        int n0 = s*448 + it*64;
        #pragma unroll
        for (int i = 0; i < 8; i++){
            int e = tid + i*256; int r = e >> 5, c = e & 31;
            long long rowb = (long long)(b*NPOS + n0 + r) * 768;
            qs[r][c] = __bfloat162float(qkv[rowb + hh*32 + c])       * invn[b*512 + hh*32 + c];
            ks[r][c] = __bfloat162float(qkv[rowb + 256 + hh*32 + c]) * invn[b*512 + 256 + hh*32 + c];
        }
        __syncthreads();
        #pragma unroll 4
        for (int r = 0; r < 64; r++){
            float qv = qs[r][d];
            #pragma unroll
            for (int j = 0; j < 4; j++) acc[j] += qv * ks[r][e0+j];
        }
        __syncthreads();
    }
    #pragma unroll
    for (int j = 0; j < 4; j++)
        part[(long long)bz*1024 + d*32 + e0 + j] = acc[j];
}
__global__ __launch_bounds__(256) void chanattn_qk_fin(const float* __restrict__ part, const float* __restrict__ temp,
                                                       float* __restrict__ attn){
    __shared__ float att_s[32][33];
    int bh = blockIdx.x;
    int hh = bh & 7;
    int tid = threadIdx.x;
    int d = tid >> 3, e0 = (tid & 7) * 4;
    float t = temp[hh];
    #pragma unroll
    for (int j = 0; j < 4; j++){
        float s = 0.f;
        for (int sp = 0; sp < TNS; sp++)
            s += part[((long long)bh*TNS + sp)*1024 + d*32 + e0 + j];
        att_s[d][e0+j] = s * t;
    }
    __syncthreads();
    if (tid < 32){
        float m = -1e30f;
        for (int e = 0; e < 32; e++) m = fmaxf(m, att_s[tid][e]);
        float s = 0.f;
        for (int e = 0; e < 32; e++){ float ev = expf(att_s[tid][e] - m); att_s[tid][e] = ev; s += ev; }
        float inv = 1.f / s;
        for (int e = 0; e < 32; e++) att_s[tid][e] *= inv;
    }
    __syncthreads();
    #pragma unroll
    for (int j = 0; j < 4; j++)
        attn[(long long)bh*1024 + d*32 + e0 + j] = att_s[d][e0+j];
}

// ---------------- channel-attn AV ----------------
__global__ __launch_bounds__(256) void chanattn_av(const bf16* __restrict__ qkv, const float* __restrict__ attn,
                                                   bf16* __restrict__ out){
    __shared__ float vsh[256];
    long long n = blockIdx.x;
    int b = (int)(n / NPOS);
    int c = threadIdx.x;
    vsh[c] = __bfloat162float(qkv[n*768 + 512 + c]);
    __syncthreads();
    int hh = c >> 5;
    const float* arow = attn + ((long long)(b*8+hh)*32 + (c & 31))*32;
    float s = 0.f;
    #pragma unroll
    for (int e = 0; e < 32; e++) s += arow[e] * vsh[hh*32 + e];
    out[n*256 + c] = __float2bfloat16(s);
}

// ---------------- orchestration ----------------
extern "C" void kernel_launch(void* const* d_in, const int* in_sizes, int n_in,
                              void* d_out, int out_size, void* d_ws, size_t ws_size,
                              hipStream_t stream){
    const float* x     = (const float*)d_in[0];
    const float* ln1g  = (const float*)d_in[3];
    const float* ln1b  = (const float*)d_in[4];
    const float* eakw  = (const float*)d_in[5];
    const float* eakb  = (const float*)d_in[6];
    const float* eaqw  = (const float*)d_in[7];
    const float* eaqb  = (const float*)d_in[8];
    const float* eavw  = (const float*)d_in[9];
    const float* eavb  = (const float*)d_in[10];
    const float* earw  = (const float*)d_in[11];
    const float* earb  = (const float*)d_in[12];
    const float* ln2g  = (const float*)d_in[13];
    const float* ln2b  = (const float*)d_in[14];
    const float* m1w1  = (const float*)d_in[15];
    const float* m1b1  = (const float*)d_in[16];
    const float* m1dww = (const float*)d_in[17];
    const float* m1dwb = (const float*)d_in[18];
    const float* m1lg  = (const float*)d_in[19];
    const float* m1lb  = (const float*)d_in[20];
    const float* m1w2  = (const float*)d_in[21];
    const float* m1b2  = (const float*)d_in[22];
    const float* ln3g  = (const float*)d_in[23];
    const float* ln3b  = (const float*)d_in[24];
    const float* catemp= (const float*)d_in[25];
    const float* caqkvw= (const float*)d_in[26];
    const float* capw  = (const float*)d_in[27];
    const float* capb  = (const float*)d_in[28];
    const float* ln4g  = (const float*)d_in[29];
    const float* ln4b  = (const float*)d_in[30];
    const float* m2w1  = (const float*)d_in[31];
    const float* m2b1  = (const float*)d_in[32];
    const float* m2dww = (const float*)d_in[33];
    const float* m2dwb = (const float*)d_in[34];
    const float* m2lg  = (const float*)d_in[35];
    const float* m2lb  = (const float*)d_in[36];
    const float* m2w2  = (const float*)d_in[37];
    const float* m2b2  = (const float*)d_in[38];

    // Workspace ~155 MB (known safe < 209 MB).
    char* base = (char*)d_ws;
    auto alloc = [&](size_t nbytes){ char* p = base; base += (nbytes + 255) & ~(size_t)255; return p; };
    constexpr size_t SZ = (size_t)MTOT*CDIM*4;
    float* R  = (float*)alloc(SZ);
    float* A0 = (float*)alloc(SZ);
    float* A1 = (float*)alloc(SZ);
    float* B0 = (float*)alloc(SZ);
    float* B1 = (float*)alloc(SZ);
    bf16* A0b  = (bf16*)A0;
    bf16* qb   = A0b + (size_t)MTOT*CDIM;
    bf16* vb   = (bf16*)A1;
    bf16* kb   = (bf16*)B1;
    bf16* attb = (bf16*)B0;
    bf16* l2b  = (bf16*)A1;
    bf16* F    = (bf16*)B0;
    bf16* G    = (bf16*)A0;
    bf16* l3b  = (bf16*)B0;
    bf16* Qb   = (bf16*)A0;
    bf16* avb  = (bf16*)B0;
    bf16* l4b  = (bf16*)A0;
    bf16* ctxb = (bf16*)alloc((size_t)BATCH*CDIM*CDIM*2);
    float* lmax = (float*)alloc((size_t)BATCH*NCHUNK*CDIM*4);
    float* lsum = (float*)alloc((size_t)BATCH*NCHUNK*CDIM*4);
    float* gmax = (float*)alloc((size_t)BATCH*CDIM*4);
    float* ginv = (float*)alloc((size_t)BATCH*CDIM*4);
    float* lss  = (float*)alloc((size_t)BATCH*NCHUNK*512*4);
    float* invn = (float*)alloc((size_t)BATCH*512*4);
    float* attnb= (float*)alloc((size_t)BATCH*8*32*32*4);
    float* ptn  = (float*)alloc((size_t)BATCH*TNS*CDIM*CDIM*4);
    float* pqk  = (float*)alloc((size_t)BATCH*8*TNS*1024*4);
    bf16* wbuf  = (bf16*)alloc((size_t)1572864*2);           // converted weights (3 MB)
    float* wT1  = (float*)alloc((size_t)9216*4);             // transposed dwconv weights
    float* wT2  = (float*)alloc((size_t)9216*4);

    // converted-weight layout
    bf16* eakw_b   = wbuf;
    bf16* eaqw_b   = wbuf + 65536;
    bf16* eavw_b   = wbuf + 131072;
    bf16* earw_b   = wbuf + 196608;
    bf16* m1w1_b   = wbuf + 262144;
    bf16* m1w2_b   = wbuf + 524288;
    bf16* caqkvw_b = wbuf + 786432;
    bf16* capw_b   = wbuf + 983040;
    bf16* m2w1_b   = wbuf + 1048576;
    bf16* m2w2_b   = wbuf + 1310720;

    dim3 blk(256);
    constexpr int MB = MTOT/128;            // 196
    long long sA1 = (long long)NPOS*CDIM;
    long long sB1 = (long long)CDIM*CDIM;

    // ---- weight prep (once per launch) ----
    {
        WArgs wa;
        const float* srcs[10] = {eakw, eaqw, eavw, earw, m1w1, m1w2, caqkvw, capw, m2w1, m2w2};
        bf16* dsts[10] = {eakw_b, eaqw_b, eavw_b, earw_b, m1w1_b, m1w2_b, caqkvw_b, capw_b, m2w1_b, m2w2_b};
        int ns[10] = {65536, 65536, 65536, 65536, 262144, 262144, 196608, 65536, 262144, 262144};
        for (int i = 0; i < 10; i++){ wa.src[i]=srcs[i]; wa.dst[i]=dsts[i]; wa.n[i]=ns[i]; }
        wcvt_kernel<<<dim3(128,10), blk, 0, stream>>>(wa);
        wtrans_kernel<<<dim3(36,2), blk, 0, stream>>>(m1dww, m2dww, wT1, wT2);
    }

    // ---- Stage 1: EfficientAttention ----
    ln4_kernel<bf16><<<MTOT/4, blk, 0, stream>>>(x, ln1g, ln1b, A0b);
    mfma_gemm<float><<<dim3(2,MB,1), blk, 0, stream>>>(A0b, eakw_b, eakb, nullptr, B0, MTOT, 256, 256, 0,0,0,0);
    mfma_gemm<float><<<dim3(2,MB,1), blk, 0, stream>>>(A0b, eaqw_b, eaqb, nullptr, B1, MTOT, 256, 256, 0,0,0,0);
    mfma_gemm<bf16><<<dim3(2,MB,1), blk, 0, stream>>>(A0b, eavw_b, eavb, nullptr, vb, MTOT, 256, 256, 0,0,0,0);
    rowsm_kernel<<<MTOT, blk, 0, stream>>>(B1, qb);
    colsm_p1<<<BATCH*NCHUNK, blk, 0, stream>>>(B0, lmax, lsum);
    colsm_p2<<<BATCH, blk, 0, stream>>>(lmax, lsum, gmax, ginv);
    colsm_p3<<<MTOT, blk, 0, stream>>>(B0, kb, gmax, ginv);
    gemm_tn_mfma<<<dim3(2,2,BATCH*TNS), blk, 0, stream>>>(vb, kb, ptn);
    ctx_reduce<<<(BATCH*65536)/256, blk, 0, stream>>>(ptn, ctxb);
    mfma_gemm<bf16><<<dim3(2,25,BATCH), blk, 0, stream>>>(qb, ctxb, nullptr, nullptr, attb,
            NPOS, 256, 256, sA1, sB1, sA1, 0);
    mfma_gemm<float><<<dim3(2,MB,1), blk, 0, stream>>>(attb, earw_b, earb, x, R, MTOT, 256, 256, 0,0,0,0);

    // ---- Stage 2: MixFFN #1 ----
    ln4_kernel<bf16><<<MTOT/4, blk, 0, stream>>>(R, ln2g, ln2b, l2b);
    mfma_gemm<bf16><<<dim3(8,MB,1), blk, 0, stream>>>(l2b, m1w1_b, m1b1, nullptr, F, MTOT, 1024, 256, 0,0,0,0);
    dwconv_ln_gelu_kernel<<<BATCH*HH*14, blk, 0, stream>>>(F, wT1, m1dwb, m1lg, m1lb, G);
    mfma_gemm<float><<<dim3(2,MB,1), blk, 0, stream>>>(G, m1w2_b, m1b2, R, R, MTOT, 256, 1024, 0,0,0,0);

    // ---- Stage 3: ChannelAttention ----
    ln4_kernel<bf16><<<MTOT/4, blk, 0, stream>>>(R, ln3g, ln3b, l3b);
    mfma_gemm<bf16><<<dim3(6,MB,1), blk, 0, stream>>>(l3b, caqkvw_b, nullptr, nullptr, Qb, MTOT, 768, 256, 0,0,0,0);
    ssq_p1<<<BATCH*NCHUNK, blk, 0, stream>>>(Qb, lss);
    ssq_p2<<<dim3(BATCH,2), blk, 0, stream>>>(lss, invn);
    chanattn_qk_part<<<BATCH*8*TNS, blk, 0, stream>>>(Qb, invn, pqk);
    chanattn_qk_fin<<<BATCH*8, blk, 0, stream>>>(pqk, catemp, attnb);
    chanattn_av<<<MTOT, blk, 0, stream>>>(Qb, attnb, avb);
    mfma_gemm<float><<<dim3(2,MB,1), blk, 0, stream>>>(avb, capw_b, capb, R, R, MTOT, 256, 256, 0,0,0,0);

    // ---- Stage 4: MixFFN #2 ----
    ln4_kernel<bf16><<<MTOT/4, blk, 0, stream>>>(R, ln4g, ln4b, l4b);
    mfma_gemm<bf16><<<dim3(8,MB,1), blk, 0, stream>>>(l4b, m2w1_b, m2b1, nullptr, F, MTOT, 1024, 256, 0,0,0,0);
    dwconv_ln_gelu_kernel<<<BATCH*HH*14, blk, 0, stream>>>(F, wT2, m2dwb, m2lg, m2lb, G);
    mfma_gemm<float><<<dim3(2,MB,1), blk, 0, stream>>>(G, m2w2_b, m2b2, R, (float*)d_out, MTOT, 256, 1024, 0,0,0,0);
}

// Round 8
// 844.381 us; speedup vs baseline: 3.4663x; 1.1339x over previous
//
#include <hip/hip_runtime.h>
#include <hip/hip_bf16.h>

typedef __hip_bfloat16 bf16;
typedef __attribute__((ext_vector_type(8))) short short8;
typedef __attribute__((ext_vector_type(4))) float floatx4;

#define DI __device__ __forceinline__

DI float ldf(const float* p, long long i){ return p[i]; }
DI float ldf(const bf16* p, long long i){ return __bfloat162float(p[i]); }
DI void stf(float* p, long long i, float v){ p[i] = v; }
DI void stf(bf16* p, long long i, float v){ p[i] = __float2bfloat16(v); }

DI unsigned short bfbits(float f){
    bf16 h = __float2bfloat16(f);
    return *reinterpret_cast<unsigned short*>(&h);
}
DI float bu(unsigned short u){
    union { unsigned int i; float f; } x; x.i = ((unsigned int)u) << 16; return x.f;
}

static constexpr int BATCH = 8;
static constexpr int HH = 56, WW = 56;
static constexpr int NPOS = HH * WW;        // 3136
static constexpr int CDIM = 256;
static constexpr int HIDD = 1024;
static constexpr int MTOT = BATCH * NPOS;   // 25088
static constexpr int NCHUNK = 49;           // 3136 / 64
static constexpr int LP = 40;               // LDS row pitch (shorts)
static constexpr int TNS = 7;               // split-K for ctx TN gemm

// ---------------- weight f32 -> bf16 pre-convert ----------------
struct WArgs {
    const float* src[10];
    bf16* dst[10];
    int n[10];
};
__global__ __launch_bounds__(256) void wcvt_kernel(WArgs a){
    int wid = blockIdx.y;
    int i = (blockIdx.x*256 + threadIdx.x) * 8;
    if (i >= a.n[wid]) return;
    const float* s = a.src[wid] + i;
    float4 f0 = *(const float4*)(s);
    float4 f1 = *(const float4*)(s + 4);
    union { uint4 u; unsigned short us[8]; } p;
    p.us[0]=bfbits(f0.x); p.us[1]=bfbits(f0.y); p.us[2]=bfbits(f0.z); p.us[3]=bfbits(f0.w);
    p.us[4]=bfbits(f1.x); p.us[5]=bfbits(f1.y); p.us[6]=bfbits(f1.z); p.us[7]=bfbits(f1.w);
    *(uint4*)(a.dst[wid] + i) = p.u;
}

__global__ __launch_bounds__(256) void wtrans_kernel(const float* __restrict__ w1, const float* __restrict__ w2,
                                                     float* __restrict__ t1, float* __restrict__ t2){
    int i = blockIdx.x*256 + threadIdx.x;   // 0..9215
    const float* w = blockIdx.y ? w2 : w1;
    float* t = blockIdx.y ? t2 : t1;
    int tap = i >> 10, c = i & 1023;
    t[i] = w[c*9 + tap];
}

// ---------------- MFMA bf16 GEMM (NT: B[n,k], both bf16; A row stride lda) ----------------
template<typename TC>
__global__ __launch_bounds__(256) void mfma_gemm(
    const bf16* __restrict__ A, const bf16* __restrict__ Bw,
    const float* __restrict__ bias, const float* __restrict__ addend,
    TC* __restrict__ C, int M, int N, int K, int lda,
    long long strA, long long strB, long long strC, long long strAdd)
{
    __shared__ short As[128*LP];
    __shared__ short Bs[128*LP];
    int tid = threadIdx.x;
    int bz = blockIdx.z;
    A  += (long long)bz * strA;
    Bw += (long long)bz * strB;
    C  += (long long)bz * strC;
    if (addend) addend += (long long)bz * strAdd;
    int n0 = blockIdx.x * 128, m0 = blockIdx.y * 128;
    int w = tid >> 6, lane = tid & 63, lm = lane & 15, quad = lane >> 4;
    int mw = (w >> 1) * 64, nw = (w & 1) * 64;

    floatx4 z = {0.f, 0.f, 0.f, 0.f};
    floatx4 acc[4][4];
    #pragma unroll
    for (int mi = 0; mi < 4; mi++)
        #pragma unroll
        for (int ni = 0; ni < 4; ni++) acc[mi][ni] = z;

    for (int k0 = 0; k0 < K; k0 += 32){
        #pragma unroll
        for (int cc = 0; cc < 2; cc++){
            int c = tid + cc*256;
            int row = c >> 2, col8 = (c & 3) * 8;
            int rg = m0 + row; if (rg > M-1) rg = M-1;
            *(uint4*)&As[row*LP + col8] = *(const uint4*)(A + (long long)rg*lda + k0 + col8);
            *(uint4*)&Bs[row*LP + col8] = *(const uint4*)(Bw + (long long)(n0+row)*K + k0 + col8);
        }
        __syncthreads();
        short8 af[4], bfr[4];
        #pragma unroll
        for (int mi = 0; mi < 4; mi++)
            af[mi] = *(const short8*)&As[(mw + mi*16 + lm)*LP + quad*8];
        #pragma unroll
        for (int ni = 0; ni < 4; ni++)
            bfr[ni] = *(const short8*)&Bs[(nw + ni*16 + lm)*LP + quad*8];
        #pragma unroll
        for (int mi = 0; mi < 4; mi++)
            #pragma unroll
            for (int ni = 0; ni < 4; ni++)
                acc[mi][ni] = __builtin_amdgcn_mfma_f32_16x16x32_bf16(af[mi], bfr[ni], acc[mi][ni], 0, 0, 0);
        __syncthreads();
    }

    #pragma unroll
    for (int ni = 0; ni < 4; ni++){
        int cg = n0 + nw + ni*16 + lm;
        float bv = bias ? bias[cg] : 0.f;
        #pragma unroll
        for (int mi = 0; mi < 4; mi++){
            #pragma unroll
            for (int r = 0; r < 4; r++){
                int rg = m0 + mw + mi*16 + quad*4 + r;
                if (rg < M){
                    long long idx = (long long)rg*N + cg;
                    float v = acc[mi][ni][r] + bv;
                    if (addend) v += addend[idx];
                    stf(C, idx, v);
                }
            }
        }
    }
}

// ---------------- MFMA bf16 TN GEMM: part[s][vc][kc] = sum_{n in split s} V[n,vc]*K[n,kc] ----------------
__global__ __launch_bounds__(256) void gemm_tn_mfma(const bf16* __restrict__ V, const bf16* __restrict__ Kb,
                                                    float* __restrict__ part){
    __shared__ short As[128*LP];
    __shared__ short Bs[128*LP];
    int tid = threadIdx.x;
    int bz = blockIdx.z;           // b*TNS + s
    int b = bz / TNS, s = bz % TNS;
    const bf16* Vb = V  + (long long)b*NPOS*CDIM;
    const bf16* Kc = Kb + (long long)b*NPOS*CDIM;
    int m0 = blockIdx.y * 128, n0 = blockIdx.x * 128;
    int w = tid >> 6, lane = tid & 63, lm = lane & 15, quad = lane >> 4;
    int mw = (w >> 1) * 64, nw = (w & 1) * 64;

    floatx4 z = {0.f,0.f,0.f,0.f};
    floatx4 acc[4][4];
    #pragma unroll
    for (int mi = 0; mi < 4; mi++)
        #pragma unroll
        for (int ni = 0; ni < 4; ni++) acc[mi][ni] = z;

    int r = tid & 31, cgrp = tid >> 5;

    for (int step = 0; step < 448/32; step++){
        int nb = s*448 + step*32;
        #pragma unroll
        for (int cc = 0; cc < 2; cc++){
            int ch = cgrp*8 + cc*64;
            short8 va = *(const short8*)(Vb + (long long)(nb + r)*CDIM + m0 + ch);
            short8 ka = *(const short8*)(Kc + (long long)(nb + r)*CDIM + n0 + ch);
            #pragma unroll
            for (int i = 0; i < 8; i++){
                As[(ch+i)*LP + r] = va[i];
                Bs[(ch+i)*LP + r] = ka[i];
            }
        }
        __syncthreads();
        short8 af[4], bfr[4];
        #pragma unroll
        for (int mi = 0; mi < 4; mi++)
            af[mi] = *(const short8*)&As[(mw + mi*16 + lm)*LP + quad*8];
        #pragma unroll
        for (int ni = 0; ni < 4; ni++)
            bfr[ni] = *(const short8*)&Bs[(nw + ni*16 + lm)*LP + quad*8];
        #pragma unroll
        for (int mi = 0; mi < 4; mi++)
            #pragma unroll
            for (int ni = 0; ni < 4; ni++)
                acc[mi][ni] = __builtin_amdgcn_mfma_f32_16x16x32_bf16(af[mi], bfr[ni], acc[mi][ni], 0, 0, 0);
        __syncthreads();
    }

    float* pb = part + (long long)bz * CDIM * CDIM;
    #pragma unroll
    for (int ni = 0; ni < 4; ni++){
        int cg = n0 + nw + ni*16 + lm;
        #pragma unroll
        for (int mi = 0; mi < 4; mi++){
            #pragma unroll
            for (int rr = 0; rr < 4; rr++){
                int rg = m0 + mw + mi*16 + quad*4 + rr;
                pb[(long long)rg*CDIM + cg] = acc[mi][ni][rr];
            }
        }
    }
}

__global__ __launch_bounds__(256) void ctx_reduce(const float* __restrict__ part, bf16* __restrict__ ctxb){
    long long idx = (long long)blockIdx.x*256 + threadIdx.x;
    int b = (int)(idx >> 16);
    int rem = (int)(idx & 65535);
    float s = 0.f;
    #pragma unroll
    for (int sp = 0; sp < TNS; sp++)
        s += part[((long long)(b*TNS+sp) << 16) + rem];
    ctxb[idx] = __float2bfloat16(s);
}

// ---------------- LayerNorm: one wave per row ----------------
DI void st4o(float* p, long long i, float a, float b, float c, float d){
    float4 v = make_float4(a,b,c,d); *(float4*)(p + i) = v;
}
DI void st4o(bf16* p, long long i, float a, float b, float c, float d){
    union { unsigned long long u; unsigned short us[4]; } pk;
    pk.us[0]=bfbits(a); pk.us[1]=bfbits(b); pk.us[2]=bfbits(c); pk.us[3]=bfbits(d);
    *(unsigned long long*)(p + i) = pk.u;
}
template<typename TOUT>
__global__ __launch_bounds__(256) void ln4_kernel(const float* __restrict__ x, const float* __restrict__ g,
                                                  const float* __restrict__ b, TOUT* __restrict__ y){
    int wv = threadIdx.x >> 6, lane = threadIdx.x & 63;
    long long row = (long long)blockIdx.x*4 + wv;
    float4 v = *(const float4*)(x + row*256 + lane*4);
    float s  = v.x + v.y + v.z + v.w;
    float ss = v.x*v.x + v.y*v.y + v.z*v.z + v.w*v.w;
    #pragma unroll
    for (int off = 32; off > 0; off >>= 1){
        s  += __shfl_down(s,  off);
        ss += __shfl_down(ss, off);
    }
    s = __shfl(s, 0); ss = __shfl(ss, 0);
    float mean = s * (1.f/256.f);
    float var  = ss * (1.f/256.f) - mean*mean;
    float inv  = rsqrtf(var + 1e-5f);
    float4 gv = *(const float4*)(g + lane*4);
    float4 bv = *(const float4*)(b + lane*4);
    st4o(y, row*256 + lane*4,
         (v.x-mean)*inv*gv.x + bv.x, (v.y-mean)*inv*gv.y + bv.y,
         (v.z-mean)*inv*gv.z + bv.z, (v.w-mean)*inv*gv.w + bv.w);
}

// ---------------- column softmax over N (for k) ----------------
__global__ __launch_bounds__(256) void colsm_p1(const float* __restrict__ x, float* __restrict__ lmax, float* __restrict__ lsum){
    int b = blockIdx.x / NCHUNK, ch = blockIdx.x % NCHUNK;
    int c = threadIdx.x;
    const float* base = x + ((long long)b*NPOS + ch*64)*CDIM + c;
    float m = -1e30f;
    for (int r = 0; r < 64; r++) m = fmaxf(m, base[(long long)r*CDIM]);
    float s = 0.f;
    for (int r = 0; r < 64; r++) s += expf(base[(long long)r*CDIM] - m);
    lmax[(long long)blockIdx.x*CDIM + c] = m;
    lsum[(long long)blockIdx.x*CDIM + c] = s;
}
__global__ __launch_bounds__(256) void colsm_p2(const float* __restrict__ lmax, const float* __restrict__ lsum,
                                                float* __restrict__ gmax, float* __restrict__ ginv){
    int b = blockIdx.x; int c = threadIdx.x;
    float g = -1e30f;
    for (int ch = 0; ch < NCHUNK; ch++) g = fmaxf(g, lmax[((long long)b*NCHUNK+ch)*CDIM + c]);
    float s = 0.f;
    for (int ch = 0; ch < NCHUNK; ch++)
        s += lsum[((long long)b*NCHUNK+ch)*CDIM + c] * expf(lmax[((long long)b*NCHUNK+ch)*CDIM + c] - g);
    gmax[b*CDIM + c] = g; ginv[b*CDIM + c] = 1.f / s;
}
__global__ __launch_bounds__(256) void colsm_p3(const float* __restrict__ x, bf16* __restrict__ y,
                                                const float* __restrict__ gmax, const float* __restrict__ ginv){
    long long idx = (long long)blockIdx.x*256 + threadIdx.x;
    int c = idx & (CDIM-1);
    int b = (int)(idx / ((long long)NPOS*CDIM));
    y[idx] = __float2bfloat16(expf(x[idx] - gmax[b*CDIM + c]) * ginv[b*CDIM + c]);
}

// ---------------- row softmax over C=256 (q): wave-per-row, 4 rows/block ----------------
__global__ __launch_bounds__(256) void rowsm4_kernel(const float* __restrict__ x, bf16* __restrict__ y){
    int wv = threadIdx.x >> 6, lane = threadIdx.x & 63;
    long long row = (long long)blockIdx.x*4 + wv;
    float4 v = *(const float4*)(x + row*256 + lane*4);
    float m = fmaxf(fmaxf(v.x, v.y), fmaxf(v.z, v.w));
    #pragma unroll
    for (int off = 32; off > 0; off >>= 1) m = fmaxf(m, __shfl_down(m, off));
    m = __shfl(m, 0);
    float e0 = expf(v.x - m), e1 = expf(v.y - m), e2 = expf(v.z - m), e3 = expf(v.w - m);
    float s = e0 + e1 + e2 + e3;
    #pragma unroll
    for (int off = 32; off > 0; off >>= 1) s += __shfl_down(s, off);
    s = __shfl(s, 0);
    float inv = 1.f / s;
    st4o(y, row*256 + lane*4, e0*inv, e1*inv, e2*inv, e3*inv);
}

// ---------------- fused dwconv3x3 + skip + LN + GELU, LDS-tiled ----------------
__global__ __launch_bounds__(256) void dwconv_ln_gelu_kernel(const bf16* __restrict__ f, const float* __restrict__ wT,
        const float* __restrict__ db, const float* __restrict__ lg, const float* __restrict__ lb, bf16* __restrict__ out){
    __shared__ short Ls[18*1024];
    __shared__ float r1[2][2][128], r2[2][2][128];
    int tid = threadIdx.x;
    int blk = blockIdx.x;
    int b = blk / 784;
    int rem = blk % 784;
    int h = rem / 14, w0 = (rem % 14) * 4;
    const bf16* fb = f + (long long)b * NPOS * HIDD;

    #pragma unroll
    for (int j = 0; j < 9; j++){
        int idx = j*256 + tid;
        int rc = idx >> 7, chunk = idx & 127;
        int row = rc / 6, col = rc % 6;
        int hy = h - 1 + row, wx = w0 - 1 + col;
        uint4 v = {0,0,0,0};
        if (hy >= 0 && hy < HH && wx >= 0 && wx < WW)
            v = *(const uint4*)(fb + (long long)(hy*WW + wx)*HIDD + chunk*8);
        *(uint4*)&Ls[rc*1024 + chunk*8] = v;
    }
    __syncthreads();

    int ph = tid >> 7, ct = tid & 127;
    int c0 = ct * 8;
    float sv[2][8];
    {
        float4 d0 = *(const float4*)(db + c0);
        float4 d1 = *(const float4*)(db + c0 + 4);
        #pragma unroll
        for (int pp = 0; pp < 2; pp++){
            sv[pp][0]=d0.x; sv[pp][1]=d0.y; sv[pp][2]=d0.z; sv[pp][3]=d0.w;
            sv[pp][4]=d1.x; sv[pp][5]=d1.y; sv[pp][6]=d1.z; sv[pp][7]=d1.w;
        }
    }
    #pragma unroll
    for (int tap = 0; tap < 9; tap++){
        int ky = tap / 3, kx = tap % 3;
        float4 w0v = *(const float4*)(wT + tap*1024 + c0);
        float4 w1v = *(const float4*)(wT + tap*1024 + c0 + 4);
        float wv[8] = {w0v.x,w0v.y,w0v.z,w0v.w,w1v.x,w1v.y,w1v.z,w1v.w};
        #pragma unroll
        for (int pp = 0; pp < 2; pp++){
            int pos_local = 2*ph + pp;
            short8 val = *(const short8*)&Ls[(ky*6 + pos_local + kx)*1024 + c0];
            #pragma unroll
            for (int i = 0; i < 8; i++){
                float fv = bu((unsigned short)val[i]);
                sv[pp][i] += fv * wv[i];
                if (tap == 4) sv[pp][i] += fv;
            }
        }
    }
    #pragma unroll
    for (int pp = 0; pp < 2; pp++){
        float s = 0.f, ss = 0.f;
        #pragma unroll
        for (int i = 0; i < 8; i++){ s += sv[pp][i]; ss += sv[pp][i]*sv[pp][i]; }
        r1[ph][pp][ct] = s; r2[ph][pp][ct] = ss;
    }
    __syncthreads();
    for (int st = 64; st > 0; st >>= 1){
        if (ct < st){
            #pragma unroll
            for (int pp = 0; pp < 2; pp++){
                r1[ph][pp][ct] += r1[ph][pp][ct+st];
                r2[ph][pp][ct] += r2[ph][pp][ct+st];
            }
        }
        __syncthreads();
    }
    float4 g0 = *(const float4*)(lg + c0), g1 = *(const float4*)(lg + c0 + 4);
    float4 b0 = *(const float4*)(lb + c0), b1 = *(const float4*)(lb + c0 + 4);
    float gg[8] = {g0.x,g0.y,g0.z,g0.w,g1.x,g1.y,g1.z,g1.w};
    float bb[8] = {b0.x,b0.y,b0.z,b0.w,b1.x,b1.y,b1.z,b1.w};
    #pragma unroll
    for (int pp = 0; pp < 2; pp++){
        int pos_local = 2*ph + pp;
        long long n = (long long)b*NPOS + h*WW + (w0 + pos_local);
        float mean = r1[ph][pp][0] * (1.f/HIDD);
        float var  = r2[ph][pp][0] * (1.f/HIDD) - mean*mean;
        float inv  = rsqrtf(var + 1e-5f);
        union { uint4 u; unsigned short us[8]; } ov;
        #pragma unroll
        for (int i = 0; i < 8; i++){
            float o = (sv[pp][i]-mean)*inv*gg[i] + bb[i];
            o = 0.5f*o*(1.f + erff(o*0.70710678118654752f));
            ov.us[i] = bfbits(o);
        }
        *(uint4*)(out + n*HIDD + c0) = ov.u;
    }
}

// ---------------- channel-attn: per-channel sum-sq over N ----------------
__global__ __launch_bounds__(256) void ssq_p1(const bf16* __restrict__ qkv, float* __restrict__ lss){
    __shared__ float red[4][64][8];
    int b = blockIdx.x / NCHUNK, ch = blockIdx.x % NCHUNK;
    int tid = threadIdx.x;
    int col = (tid & 63) * 8;
    int rg = tid >> 6;
    float s[8] = {0,0,0,0,0,0,0,0};
    for (int r = rg*16; r < rg*16 + 16; r++){
        long long row = (long long)(b*NPOS + ch*64 + r);
        union { uint4 u; unsigned short us[8]; } v;
        v.u = *(const uint4*)(qkv + row*768 + col);
        #pragma unroll
        for (int i = 0; i < 8; i++){ float f = bu(v.us[i]); s[i] += f*f; }
    }
    #pragma unroll
    for (int i = 0; i < 8; i++) red[rg][tid & 63][i] = s[i];
    __syncthreads();
    if (tid < 64){
        #pragma unroll
        for (int i = 0; i < 8; i++){
            float t = red[0][tid][i] + red[1][tid][i] + red[2][tid][i] + red[3][tid][i];
            lss[(long long)blockIdx.x*512 + tid*8 + i] = t;
        }
    }
}
__global__ __launch_bounds__(256) void ssq_p2(const float* __restrict__ lss, float* __restrict__ invn){
    int b = blockIdx.x; int c = blockIdx.y*256 + threadIdx.x;
    float s = 0.f;
    for (int ch = 0; ch < NCHUNK; ch++) s += lss[((long long)b*NCHUNK+ch)*512 + c];
    invn[b*512 + c] = 1.f / fmaxf(sqrtf(s), 1e-12f);
}

// ---------------- channel-attn QK partials (vectorized staging) ----------------
__global__ __launch_bounds__(256) void chanattn_qk_part(const bf16* __restrict__ qkv, const float* __restrict__ invn,
                                                        float* __restrict__ part){
    __shared__ float qs[64][36];
    __shared__ float ks[64][36];
    int bz = blockIdx.x;               // (b*8+hh)*TNS + s
    int bh = bz / TNS, s = bz % TNS;
    int b = bh >> 3, hh = bh & 7;
    int tid = threadIdx.x;
    int d = tid >> 3, e0 = (tid & 7) * 4;
    // staging coords: thread -> (row r = tid>>2, chunk c8 = (tid&3)*8)
    int sr = tid >> 2, sc8 = (tid & 3) * 8;
    float invq[8], invk[8];
    {
        float4 a0 = *(const float4*)(invn + b*512 + hh*32 + sc8);
        float4 a1 = *(const float4*)(invn + b*512 + hh*32 + sc8 + 4);
        float4 b0 = *(const float4*)(invn + b*512 + 256 + hh*32 + sc8);
        float4 b1 = *(const float4*)(invn + b*512 + 256 + hh*32 + sc8 + 4);
        invq[0]=a0.x; invq[1]=a0.y; invq[2]=a0.z; invq[3]=a0.w;
        invq[4]=a1.x; invq[5]=a1.y; invq[6]=a1.z; invq[7]=a1.w;
        invk[0]=b0.x; invk[1]=b0.y; invk[2]=b0.z; invk[3]=b0.w;
        invk[4]=b1.x; invk[5]=b1.y; invk[6]=b1.z; invk[7]=b1.w;
    }
    float acc[4] = {0.f,0.f,0.f,0.f};
    for (int it = 0; it < 7; it++){
        int n0 = s*448 + it*64;
        {
            long long rowb = (long long)(b*NPOS + n0 + sr) * 768;
            union { uint4 u; unsigned short us[8]; } qv, kv;
            qv.u = *(const uint4*)(qkv + rowb + hh*32 + sc8);
            kv.u = *(const uint4*)(qkv + rowb + 256 + hh*32 + sc8);
            #pragma unroll
            for (int i = 0; i < 8; i++){
                qs[sr][sc8+i] = bu(qv.us[i]) * invq[i];
                ks[sr][sc8+i] = bu(kv.us[i]) * invk[i];
            }
        }
        __syncthreads();
        #pragma unroll 4
        for (int r = 0; r < 64; r++){
            float qv = qs[r][d];
            #pragma unroll
            for (int j = 0; j < 4; j++) acc[j] += qv * ks[r][e0+j];
        }
        __syncthreads();
    }
    #pragma unroll
    for (int j = 0; j < 4; j++)
        part[(long long)bz*1024 + d*32 + e0 + j] = acc[j];
}
__global__ __launch_bounds__(256) void chanattn_qk_fin(const float* __restrict__ part, const float* __restrict__ temp,
                                                       float* __restrict__ attn){
    __shared__ float att_s[32][33];
    int bh = blockIdx.x;
    int hh = bh & 7;
    int tid = threadIdx.x;
    int d = tid >> 3, e0 = (tid & 7) * 4;
    float t = temp[hh];
    #pragma unroll
    for (int j = 0; j < 4; j++){
        float s = 0.f;
        for (int sp = 0; sp < TNS; sp++)
            s += part[((long long)bh*TNS + sp)*1024 + d*32 + e0 + j];
        att_s[d][e0+j] = s * t;
    }
    __syncthreads();
    if (tid < 32){
        float m = -1e30f;
        for (int e = 0; e < 32; e++) m = fmaxf(m, att_s[tid][e]);
        float s = 0.f;
        for (int e = 0; e < 32; e++){ float ev = expf(att_s[tid][e] - m); att_s[tid][e] = ev; s += ev; }
        float inv = 1.f / s;
        for (int e = 0; e < 32; e++) att_s[tid][e] *= inv;
    }
    __syncthreads();
    #pragma unroll
    for (int j = 0; j < 4; j++)
        attn[(long long)bh*1024 + d*32 + e0 + j] = att_s[d][e0+j];
}

// ---------------- combined weight: W_b[o][h*32+e] = sum_d capw[o][h*32+d]*attn[b][h][d][e] ----------------
// grid (BATCH, 8): block = (b, og). thread: o_local = tid&31, h = tid>>5.
__global__ __launch_bounds__(256) void wcomb_kernel(const float* __restrict__ capw, const float* __restrict__ attn,
                                                    bf16* __restrict__ Wb){
    __shared__ float at_s[8192];       // attn[b]: [h][d][e]
    int b = blockIdx.x, og = blockIdx.y;
    int tid = threadIdx.x;
    #pragma unroll
    for (int j = 0; j < 8; j++)
        *(float4*)&at_s[tid*32 + j*4] = *(const float4*)(attn + (long long)b*8192 + tid*32 + j*4);
    __syncthreads();
    int o = og*32 + (tid & 31);
    int h = tid >> 5;
    float acc[32];
    #pragma unroll
    for (int e = 0; e < 32; e++) acc[e] = 0.f;
    for (int d = 0; d < 32; d++){
        float w = capw[(long long)o*256 + h*32 + d];
        const float* ar = &at_s[h*1024 + d*32];
        #pragma unroll
        for (int eq = 0; eq < 8; eq++){
            float4 av = *(const float4*)(ar + eq*4);
            acc[eq*4+0] += w*av.x; acc[eq*4+1] += w*av.y;
            acc[eq*4+2] += w*av.z; acc[eq*4+3] += w*av.w;
        }
    }
    bf16* dst = Wb + (long long)b*65536 + (long long)o*256 + h*32;
    #pragma unroll
    for (int eq = 0; eq < 4; eq++){
        union { uint4 u; unsigned short us[8]; } p;
        #pragma unroll
        for (int i = 0; i < 8; i++) p.us[i] = bfbits(acc[eq*8+i]);
        *(uint4*)(dst + eq*8) = p.u;
    }
}

// ---------------- orchestration ----------------
extern "C" void kernel_launch(void* const* d_in, const int* in_sizes, int n_in,
                              void* d_out, int out_size, void* d_ws, size_t ws_size,
                              hipStream_t stream){
    const float* x     = (const float*)d_in[0];
    const float* ln1g  = (const float*)d_in[3];
    const float* ln1b  = (const float*)d_in[4];
    const float* eakw  = (const float*)d_in[5];
    const float* eakb  = (const float*)d_in[6];
    const float* eaqw  = (const float*)d_in[7];
    const float* eaqb  = (const float*)d_in[8];
    const float* eavw  = (const float*)d_in[9];
    const float* eavb  = (const float*)d_in[10];
    const float* earw  = (const float*)d_in[11];
    const float* earb  = (const float*)d_in[12];
    const float* ln2g  = (const float*)d_in[13];
    const float* ln2b  = (const float*)d_in[14];
    const float* m1w1  = (const float*)d_in[15];
    const float* m1b1  = (const float*)d_in[16];
    const float* m1dww = (const float*)d_in[17];
    const float* m1dwb = (const float*)d_in[18];
    const float* m1lg  = (const float*)d_in[19];
    const float* m1lb  = (const float*)d_in[20];
    const float* m1w2  = (const float*)d_in[21];
    const float* m1b2  = (const float*)d_in[22];
    const float* ln3g  = (const float*)d_in[23];
    const float* ln3b  = (const float*)d_in[24];
    const float* catemp= (const float*)d_in[25];
    const float* caqkvw= (const float*)d_in[26];
    const float* capw  = (const float*)d_in[27];
    const float* capb  = (const float*)d_in[28];
    const float* ln4g  = (const float*)d_in[29];
    const float* ln4b  = (const float*)d_in[30];
    const float* m2w1  = (const float*)d_in[31];
    const float* m2b1  = (const float*)d_in[32];
    const float* m2dww = (const float*)d_in[33];
    const float* m2dwb = (const float*)d_in[34];
    const float* m2lg  = (const float*)d_in[35];
    const float* m2lb  = (const float*)d_in[36];
    const float* m2w2  = (const float*)d_in[37];
    const float* m2b2  = (const float*)d_in[38];

    char* base = (char*)d_ws;
    auto alloc = [&](size_t nbytes){ char* p = base; base += (nbytes + 255) & ~(size_t)255; return p; };
    constexpr size_t SZ = (size_t)MTOT*CDIM*4;
    float* R  = (float*)alloc(SZ);
    float* A0 = (float*)alloc(SZ);
    float* A1 = (float*)alloc(SZ);
    float* B0 = (float*)alloc(SZ);
    float* B1 = (float*)alloc(SZ);
    bf16* A0b  = (bf16*)A0;
    bf16* qb   = A0b + (size_t)MTOT*CDIM;
    bf16* vb   = (bf16*)A1;
    bf16* kb   = (bf16*)B1;
    bf16* attb = (bf16*)B0;
    bf16* l2b  = (bf16*)A1;
    bf16* F    = (bf16*)B0;
    bf16* G    = (bf16*)A0;
    bf16* l3b  = (bf16*)B0;
    bf16* Qb   = (bf16*)A0;
    bf16* l4b  = (bf16*)A0;
    bf16* ctxb = (bf16*)alloc((size_t)BATCH*CDIM*CDIM*2);
    float* lmax = (float*)alloc((size_t)BATCH*NCHUNK*CDIM*4);
    float* lsum = (float*)alloc((size_t)BATCH*NCHUNK*CDIM*4);
    float* gmax = (float*)alloc((size_t)BATCH*CDIM*4);
    float* ginv = (float*)alloc((size_t)BATCH*CDIM*4);
    float* lss  = (float*)alloc((size_t)BATCH*NCHUNK*512*4);
    float* invn = (float*)alloc((size_t)BATCH*512*4);
    float* attnb= (float*)alloc((size_t)BATCH*8*32*32*4);
    float* ptn  = (float*)alloc((size_t)BATCH*TNS*CDIM*CDIM*4);
    float* pqk  = (float*)alloc((size_t)BATCH*8*TNS*1024*4);
    bf16* wbuf  = (bf16*)alloc((size_t)1572864*2);
    float* wT1  = (float*)alloc((size_t)9216*4);
    float* wT2  = (float*)alloc((size_t)9216*4);
    bf16* Wcb   = (bf16*)alloc((size_t)BATCH*CDIM*CDIM*2);   // combined AV+proj weight, per batch

    bf16* eakw_b   = wbuf;
    bf16* eaqw_b   = wbuf + 65536;
    bf16* eavw_b   = wbuf + 131072;
    bf16* earw_b   = wbuf + 196608;
    bf16* m1w1_b   = wbuf + 262144;
    bf16* m1w2_b   = wbuf + 524288;
    bf16* caqkvw_b = wbuf + 786432;
    bf16* m2w1_b   = wbuf + 1048576;
    bf16* m2w2_b   = wbuf + 1310720;

    dim3 blk(256);
    constexpr int MB = MTOT/128;            // 196
    long long sA1 = (long long)NPOS*CDIM;
    long long sB1 = (long long)CDIM*CDIM;

    // ---- weight prep ----
    {
        WArgs wa;
        const float* srcs[10] = {eakw, eaqw, eavw, earw, m1w1, m1w2, caqkvw, m2w1, m2w2, m2w2};
        bf16* dsts[10] = {eakw_b, eaqw_b, eavw_b, earw_b, m1w1_b, m1w2_b, caqkvw_b, m2w1_b, m2w2_b, m2w2_b};
        int ns[10] = {65536, 65536, 65536, 65536, 262144, 262144, 196608, 262144, 262144, 0};
        for (int i = 0; i < 10; i++){ wa.src[i]=srcs[i]; wa.dst[i]=dsts[i]; wa.n[i]=ns[i]; }
        wcvt_kernel<<<dim3(128,10), blk, 0, stream>>>(wa);
        wtrans_kernel<<<dim3(36,2), blk, 0, stream>>>(m1dww, m2dww, wT1, wT2);
    }

    // ---- Stage 1: EfficientAttention ----
    ln4_kernel<bf16><<<MTOT/4, blk, 0, stream>>>(x, ln1g, ln1b, A0b);
    mfma_gemm<float><<<dim3(2,MB,1), blk, 0, stream>>>(A0b, eakw_b, eakb, nullptr, B0, MTOT, 256, 256, 256, 0,0,0,0);
    mfma_gemm<float><<<dim3(2,MB,1), blk, 0, stream>>>(A0b, eaqw_b, eaqb, nullptr, B1, MTOT, 256, 256, 256, 0,0,0,0);
    mfma_gemm<bf16><<<dim3(2,MB,1), blk, 0, stream>>>(A0b, eavw_b, eavb, nullptr, vb, MTOT, 256, 256, 256, 0,0,0,0);
    rowsm4_kernel<<<MTOT/4, blk, 0, stream>>>(B1, qb);
    colsm_p1<<<BATCH*NCHUNK, blk, 0, stream>>>(B0, lmax, lsum);
    colsm_p2<<<BATCH, blk, 0, stream>>>(lmax, lsum, gmax, ginv);
    colsm_p3<<<MTOT, blk, 0, stream>>>(B0, kb, gmax, ginv);
    gemm_tn_mfma<<<dim3(2,2,BATCH*TNS), blk, 0, stream>>>(vb, kb, ptn);
    ctx_reduce<<<(BATCH*65536)/256, blk, 0, stream>>>(ptn, ctxb);
    mfma_gemm<bf16><<<dim3(2,25,BATCH), blk, 0, stream>>>(qb, ctxb, nullptr, nullptr, attb,
            NPOS, 256, 256, 256, sA1, sB1, sA1, 0);
    mfma_gemm<float><<<dim3(2,MB,1), blk, 0, stream>>>(attb, earw_b, earb, x, R, MTOT, 256, 256, 256, 0,0,0,0);

    // ---- Stage 2: MixFFN #1 ----
    ln4_kernel<bf16><<<MTOT/4, blk, 0, stream>>>(R, ln2g, ln2b, l2b);
    mfma_gemm<bf16><<<dim3(8,MB,1), blk, 0, stream>>>(l2b, m1w1_b, m1b1, nullptr, F, MTOT, 1024, 256, 256, 0,0,0,0);
    dwconv_ln_gelu_kernel<<<BATCH*HH*14, blk, 0, stream>>>(F, wT1, m1dwb, m1lg, m1lb, G);
    mfma_gemm<float><<<dim3(2,MB,1), blk, 0, stream>>>(G, m1w2_b, m1b2, R, R, MTOT, 256, 1024, 1024, 0,0,0,0);

    // ---- Stage 3: ChannelAttention ----
    ln4_kernel<bf16><<<MTOT/4, blk, 0, stream>>>(R, ln3g, ln3b, l3b);
    mfma_gemm<bf16><<<dim3(6,MB,1), blk, 0, stream>>>(l3b, caqkvw_b, nullptr, nullptr, Qb, MTOT, 768, 256, 256, 0,0,0,0);
    ssq_p1<<<BATCH*NCHUNK, blk, 0, stream>>>(Qb, lss);
    ssq_p2<<<dim3(BATCH,2), blk, 0, stream>>>(lss, invn);
    chanattn_qk_part<<<BATCH*8*TNS, blk, 0, stream>>>(Qb, invn, pqk);
    chanattn_qk_fin<<<BATCH*8, blk, 0, stream>>>(pqk, catemp, attnb);
    wcomb_kernel<<<dim3(BATCH,8), blk, 0, stream>>>(capw, attnb, Wcb);
    // R += v @ W_b^T + capb   (v = qkv cols 512..767, row stride 768)
    mfma_gemm<float><<<dim3(2,25,BATCH), blk, 0, stream>>>(Qb + 512, Wcb, capb, R, R,
            NPOS, 256, 256, 768, (long long)NPOS*768, sB1, sA1, sA1);

    // ---- Stage 4: MixFFN #2 ----
    ln4_kernel<bf16><<<MTOT/4, blk, 0, stream>>>(R, ln4g, ln4b, l4b);
    mfma_gemm<bf16><<<dim3(8,MB,1), blk, 0, stream>>>(l4b, m2w1_b, m2b1, nullptr, F, MTOT, 1024, 256, 256, 0,0,0,0);
    dwconv_ln_gelu_kernel<<<BATCH*HH*14, blk, 0, stream>>>(F, wT2, m2dwb, m2lg, m2lb, G);
    mfma_gemm<float><<<dim3(2,MB,1), blk, 0, stream>>>(G, m2w2_b, m2b2, R, (float*)d_out, MTOT, 256, 1024, 1024, 0,0,0,0);
}

// Round 10
// 804.212 us; speedup vs baseline: 3.6394x; 1.0499x over previous
//
#include <hip/hip_runtime.h>
#include <hip/hip_bf16.h>

typedef __hip_bfloat16 bf16;
typedef __attribute__((ext_vector_type(8))) short short8;
typedef __attribute__((ext_vector_type(4))) float floatx4;

#define DI __device__ __forceinline__

DI float ldf(const float* p, long long i){ return p[i]; }
DI float ldf(const bf16* p, long long i){ return __bfloat162float(p[i]); }
DI void stf(float* p, long long i, float v){ p[i] = v; }
DI void stf(bf16* p, long long i, float v){ p[i] = __float2bfloat16(v); }

DI unsigned short bfbits(float f){
    bf16 h = __float2bfloat16(f);
    return *reinterpret_cast<unsigned short*>(&h);
}
DI float bu(unsigned short u){
    union { unsigned int i; float f; } x; x.i = ((unsigned int)u) << 16; return x.f;
}

// direct global->LDS 16B load (m97 trick). lds dest: wave-uniform base + lane*16.
DI void gload16(const void* g, void* l){
    __builtin_amdgcn_global_load_lds(
        (const __attribute__((address_space(1))) unsigned int*)g,
        (__attribute__((address_space(3))) unsigned int*)l,
        16, 0, 0);
}

static constexpr int BATCH = 8;
static constexpr int HH = 56, WW = 56;
static constexpr int NPOS = HH * WW;        // 3136
static constexpr int CDIM = 256;
static constexpr int HIDD = 1024;
static constexpr int MTOT = BATCH * NPOS;   // 25088
static constexpr int NCHUNK = 49;           // 3136 / 64
static constexpr int LP = 40;               // LDS pitch for tn gemm (shorts)
static constexpr int TNS = 7;               // split-K for ctx TN gemm

// ---------------- weight f32 -> bf16 pre-convert ----------------
struct WArgs {
    const float* src[10];
    bf16* dst[10];
    int n[10];
};
__global__ __launch_bounds__(256) void wcvt_kernel(WArgs a){
    int wid = blockIdx.y;
    int i = (blockIdx.x*256 + threadIdx.x) * 8;
    if (i >= a.n[wid]) return;
    const float* s = a.src[wid] + i;
    float4 f0 = *(const float4*)(s);
    float4 f1 = *(const float4*)(s + 4);
    union { uint4 u; unsigned short us[8]; } p;
    p.us[0]=bfbits(f0.x); p.us[1]=bfbits(f0.y); p.us[2]=bfbits(f0.z); p.us[3]=bfbits(f0.w);
    p.us[4]=bfbits(f1.x); p.us[5]=bfbits(f1.y); p.us[6]=bfbits(f1.z); p.us[7]=bfbits(f1.w);
    *(uint4*)(a.dst[wid] + i) = p.u;
}

__global__ __launch_bounds__(256) void wtrans_kernel(const float* __restrict__ w1, const float* __restrict__ w2,
                                                     float* __restrict__ t1, float* __restrict__ t2){
    int i = blockIdx.x*256 + threadIdx.x;   // 0..9215
    const float* w = blockIdx.y ? w2 : w1;
    float* t = blockIdx.y ? t2 : t1;
    int tap = i >> 10, c = i & 1023;
    t[i] = w[c*9 + tap];
}

// ---------------- MFMA bf16 GEMM (NT), global_load_lds staging ----------------
// LDS layout: 16B chunk c holds tile[row=c>>2][col16=(c&3)^(row&3)] (XOR swizzle, no pad).
template<typename TC>
__global__ __launch_bounds__(256) void mfma_gemm(
    const bf16* __restrict__ A, const bf16* __restrict__ Bw,
    const float* __restrict__ bias, const float* __restrict__ addend,
    TC* __restrict__ C, int M, int N, int K, int lda,
    long long strA, long long strB, long long strC, long long strAdd)
{
    __shared__ short As[128*32];
    __shared__ short Bs[128*32];
    int tid = threadIdx.x;
    int bz = blockIdx.z;
    A  += (long long)bz * strA;
    Bw += (long long)bz * strB;
    C  += (long long)bz * strC;
    if (addend) addend += (long long)bz * strAdd;
    int n0 = blockIdx.x * 128, m0 = blockIdx.y * 128;
    int w = tid >> 6, lane = tid & 63, lm = lane & 15, quad = lane >> 4;
    int mw = (w >> 1) * 64, nw = (w & 1) * 64;

    // staging: wave w issues instructions t=2w,2w+1; lane covers chunk t*64+lane.
    int c0 = w*128 + lane, c1 = c0 + 64;
    int ar0 = c0 >> 2, ac0 = (c0 & 3) ^ (ar0 & 3);
    int ar1 = c1 >> 2, ac1 = (c1 & 3) ^ (ar1 & 3);
    int rgA0 = m0 + ar0; if (rgA0 > M-1) rgA0 = M-1;
    int rgA1 = m0 + ar1; if (rgA1 > M-1) rgA1 = M-1;
    short* aL0 = &As[(2*w+0)*512];
    short* aL1 = &As[(2*w+1)*512];
    short* bL0 = &Bs[(2*w+0)*512];
    short* bL1 = &Bs[(2*w+1)*512];
    const bf16* Arow0 = A + (long long)rgA0*lda + ac0*8;
    const bf16* Arow1 = A + (long long)rgA1*lda + ac1*8;
    const bf16* Brow0 = Bw + (long long)(n0+ar0)*K + ac0*8;
    const bf16* Brow1 = Bw + (long long)(n0+ar1)*K + ac1*8;

    floatx4 z = {0.f, 0.f, 0.f, 0.f};
    floatx4 acc[4][4];
    #pragma unroll
    for (int mi = 0; mi < 4; mi++)
        #pragma unroll
        for (int ni = 0; ni < 4; ni++) acc[mi][ni] = z;

    int sq = quad ^ (lm & 3);   // read-side swizzle (row&3 == lm&3 for all fragment rows)

    for (int k0 = 0; k0 < K; k0 += 32){
        gload16(Arow0 + k0, aL0);
        gload16(Arow1 + k0, aL1);
        gload16(Brow0 + k0, bL0);
        gload16(Brow1 + k0, bL1);
        __syncthreads();
        short8 af[4], bfr[4];
        #pragma unroll
        for (int mi = 0; mi < 4; mi++)
            af[mi] = *(const short8*)&As[(((mw + mi*16 + lm)<<2) + sq)*8];
        #pragma unroll
        for (int ni = 0; ni < 4; ni++)
            bfr[ni] = *(const short8*)&Bs[(((nw + ni*16 + lm)<<2) + sq)*8];
        #pragma unroll
        for (int mi = 0; mi < 4; mi++)
            #pragma unroll
            for (int ni = 0; ni < 4; ni++)
                acc[mi][ni] = __builtin_amdgcn_mfma_f32_16x16x32_bf16(af[mi], bfr[ni], acc[mi][ni], 0, 0, 0);
        __syncthreads();
    }

    #pragma unroll
    for (int ni = 0; ni < 4; ni++){
        int cg = n0 + nw + ni*16 + lm;
        float bv = bias ? bias[cg] : 0.f;
        #pragma unroll
        for (int mi = 0; mi < 4; mi++){
            #pragma unroll
            for (int r = 0; r < 4; r++){
                int rg = m0 + mw + mi*16 + quad*4 + r;
                if (rg < M){
                    long long idx = (long long)rg*N + cg;
                    float v = acc[mi][ni][r] + bv;
                    if (addend) v += addend[idx];
                    stf(C, idx, v);
                }
            }
        }
    }
}

// ---------------- MFMA bf16 TN GEMM: part[s][vc][kc] = sum_{n in split s} V[n,vc]*K[n,kc] ----------------
__global__ __launch_bounds__(256) void gemm_tn_mfma(const bf16* __restrict__ V, const bf16* __restrict__ Kb,
                                                    float* __restrict__ part){
    __shared__ short As[128*LP];
    __shared__ short Bs[128*LP];
    int tid = threadIdx.x;
    int bz = blockIdx.z;           // b*TNS + s
    int b = bz / TNS, s = bz % TNS;
    const bf16* Vb = V  + (long long)b*NPOS*CDIM;
    const bf16* Kc = Kb + (long long)b*NPOS*CDIM;
    int m0 = blockIdx.y * 128, n0 = blockIdx.x * 128;
    int w = tid >> 6, lane = tid & 63, lm = lane & 15, quad = lane >> 4;
    int mw = (w >> 1) * 64, nw = (w & 1) * 64;

    floatx4 z = {0.f,0.f,0.f,0.f};
    floatx4 acc[4][4];
    #pragma unroll
    for (int mi = 0; mi < 4; mi++)
        #pragma unroll
        for (int ni = 0; ni < 4; ni++) acc[mi][ni] = z;

    int r = tid & 31, cgrp = tid >> 5;

    for (int step = 0; step < 448/32; step++){
        int nb = s*448 + step*32;
        #pragma unroll
        for (int cc = 0; cc < 2; cc++){
            int ch = cgrp*8 + cc*64;
            short8 va = *(const short8*)(Vb + (long long)(nb + r)*CDIM + m0 + ch);
            short8 ka = *(const short8*)(Kc + (long long)(nb + r)*CDIM + n0 + ch);
            #pragma unroll
            for (int i = 0; i < 8; i++){
                As[(ch+i)*LP + r] = va[i];
                Bs[(ch+i)*LP + r] = ka[i];
            }
        }
        __syncthreads();
        short8 af[4], bfr[4];
        #pragma unroll
        for (int mi = 0; mi < 4; mi++)
            af[mi] = *(const short8*)&As[(mw + mi*16 + lm)*LP + quad*8];
        #pragma unroll
        for (int ni = 0; ni < 4; ni++)
            bfr[ni] = *(const short8*)&Bs[(nw + ni*16 + lm)*LP + quad*8];
        #pragma unroll
        for (int mi = 0; mi < 4; mi++)
            #pragma unroll
            for (int ni = 0; ni < 4; ni++)
                acc[mi][ni] = __builtin_amdgcn_mfma_f32_16x16x32_bf16(af[mi], bfr[ni], acc[mi][ni], 0, 0, 0);
        __syncthreads();
    }

    float* pb = part + (long long)bz * CDIM * CDIM;
    #pragma unroll
    for (int ni = 0; ni < 4; ni++){
        int cg = n0 + nw + ni*16 + lm;
        #pragma unroll
        for (int mi = 0; mi < 4; mi++){
            #pragma unroll
            for (int rr = 0; rr < 4; rr++){
                int rg = m0 + mw + mi*16 + quad*4 + rr;
                pb[(long long)rg*CDIM + cg] = acc[mi][ni][rr];
            }
        }
    }
}

__global__ __launch_bounds__(256) void ctx_reduce(const float* __restrict__ part, bf16* __restrict__ ctxb){
    long long idx = (long long)blockIdx.x*256 + threadIdx.x;
    int b = (int)(idx >> 16);
    int rem = (int)(idx & 65535);
    float s = 0.f;
    #pragma unroll
    for (int sp = 0; sp < TNS; sp++)
        s += part[((long long)(b*TNS+sp) << 16) + rem];
    ctxb[idx] = __float2bfloat16(s);
}

// ---------------- LayerNorm: one wave per row ----------------
DI void st4o(float* p, long long i, float a, float b, float c, float d){
    float4 v = make_float4(a,b,c,d); *(float4*)(p + i) = v;
}
DI void st4o(bf16* p, long long i, float a, float b, float c, float d){
    union { unsigned long long u; unsigned short us[4]; } pk;
    pk.us[0]=bfbits(a); pk.us[1]=bfbits(b); pk.us[2]=bfbits(c); pk.us[3]=bfbits(d);
    *(unsigned long long*)(p + i) = pk.u;
}
template<typename TOUT>
__global__ __launch_bounds__(256) void ln4_kernel(const float* __restrict__ x, const float* __restrict__ g,
                                                  const float* __restrict__ b, TOUT* __restrict__ y){
    int wv = threadIdx.x >> 6, lane = threadIdx.x & 63;
    long long row = (long long)blockIdx.x*4 + wv;
    float4 v = *(const float4*)(x + row*256 + lane*4);
    float s  = v.x + v.y + v.z + v.w;
    float ss = v.x*v.x + v.y*v.y + v.z*v.z + v.w*v.w;
    #pragma unroll
    for (int off = 32; off > 0; off >>= 1){
        s  += __shfl_down(s,  off);
        ss += __shfl_down(ss, off);
    }
    s = __shfl(s, 0); ss = __shfl(ss, 0);
    float mean = s * (1.f/256.f);
    float var  = ss * (1.f/256.f) - mean*mean;
    float inv  = rsqrtf(var + 1e-5f);
    float4 gv = *(const float4*)(g + lane*4);
    float4 bv = *(const float4*)(b + lane*4);
    st4o(y, row*256 + lane*4,
         (v.x-mean)*inv*gv.x + bv.x, (v.y-mean)*inv*gv.y + bv.y,
         (v.z-mean)*inv*gv.z + bv.z, (v.w-mean)*inv*gv.w + bv.w);
}

// ---------------- column softmax over N (k = cols 0..255 of KQ[.,512]) ----------------
// NOTE: k bias omitted upstream — softmax over N is invariant to per-column constants.
__global__ __launch_bounds__(256) void colsm_p1(const float* __restrict__ x, float* __restrict__ lmax, float* __restrict__ lsum){
    int b = blockIdx.x / NCHUNK, ch = blockIdx.x % NCHUNK;
    int c = threadIdx.x;
    const float* base = x + ((long long)b*NPOS + ch*64)*512 + c;
    float m = -1e30f;
    for (int r = 0; r < 64; r++) m = fmaxf(m, base[(long long)r*512]);
    float s = 0.f;
    for (int r = 0; r < 64; r++) s += expf(base[(long long)r*512] - m);
    lmax[(long long)blockIdx.x*CDIM + c] = m;
    lsum[(long long)blockIdx.x*CDIM + c] = s;
}
__global__ __launch_bounds__(256) void colsm_p2(const float* __restrict__ lmax, const float* __restrict__ lsum,
                                                float* __restrict__ gmax, float* __restrict__ ginv){
    int b = blockIdx.x; int c = threadIdx.x;
    float g = -1e30f;
    for (int ch = 0; ch < NCHUNK; ch++) g = fmaxf(g, lmax[((long long)b*NCHUNK+ch)*CDIM + c]);
    float s = 0.f;
    for (int ch = 0; ch < NCHUNK; ch++)
        s += lsum[((long long)b*NCHUNK+ch)*CDIM + c] * expf(lmax[((long long)b*NCHUNK+ch)*CDIM + c] - g);
    gmax[b*CDIM + c] = g; ginv[b*CDIM + c] = 1.f / s;
}
__global__ __launch_bounds__(256) void colsm_p3(const float* __restrict__ x, bf16* __restrict__ y,
                                                const float* __restrict__ gmax, const float* __restrict__ ginv){
    long long idx = (long long)blockIdx.x*256 + threadIdx.x;
    int c = (int)(idx & 255);
    long long row = idx >> 8;
    int b = (int)(row / NPOS);
    y[idx] = __float2bfloat16(expf(x[row*512 + c] - gmax[b*CDIM + c]) * ginv[b*CDIM + c]);
}

// ---------------- row softmax (q = cols 256..511 of KQ) + bias, wave-per-row ----------------
__global__ __launch_bounds__(256) void rowsm4b_kernel(const float* __restrict__ x, const float* __restrict__ bias,
                                                      bf16* __restrict__ y){
    int wv = threadIdx.x >> 6, lane = threadIdx.x & 63;
    long long row = (long long)blockIdx.x*4 + wv;
    float4 v = *(const float4*)(x + row*512 + 256 + lane*4);
    float4 bb = *(const float4*)(bias + lane*4);
    v.x += bb.x; v.y += bb.y; v.z += bb.z; v.w += bb.w;
    float m = fmaxf(fmaxf(v.x, v.y), fmaxf(v.z, v.w));
    #pragma unroll
    for (int off = 32; off > 0; off >>= 1) m = fmaxf(m, __shfl_down(m, off));
    m = __shfl(m, 0);
    float e0 = expf(v.x - m), e1 = expf(v.y - m), e2 = expf(v.z - m), e3 = expf(v.w - m);
    float s = e0 + e1 + e2 + e3;
    #pragma unroll
    for (int off = 32; off > 0; off >>= 1) s += __shfl_down(s, off);
    s = __shfl(s, 0);
    float inv = 1.f / s;
    st4o(y, row*256 + lane*4, e0*inv, e1*inv, e2*inv, e3*inv);
}

// ---------------- fused dwconv3x3 + skip + LN + GELU, LDS-tiled, XCD-swizzled ----------------
__global__ __launch_bounds__(256) void dwconv_ln_gelu_kernel(const bf16* __restrict__ f, const float* __restrict__ wT,
        const float* __restrict__ db, const float* __restrict__ lg, const float* __restrict__ lb, bf16* __restrict__ out){
    __shared__ short Ls[18*1024];
    __shared__ float r1[2][2][128], r2[2][2][128];
    int tid = threadIdx.x;
    // XCD swizzle: consecutive blockIdx -> different batch images (round-robin XCD => each
    // XCD works one image => halo rows hit its private L2).
    int b = blockIdx.x & 7;
    int rem = blockIdx.x >> 3;              // 0..783
    int h = rem / 14, w0 = (rem % 14) * 4;
    const bf16* fb = f + (long long)b * NPOS * HIDD;

    #pragma unroll
    for (int j = 0; j < 9; j++){
        int idx = j*256 + tid;
        int rc = idx >> 7, chunk = idx & 127;
        int row = rc / 6, col = rc % 6;
        int hy = h - 1 + row, wx = w0 - 1 + col;
        uint4 v = {0,0,0,0};
        if (hy >= 0 && hy < HH && wx >= 0 && wx < WW)
            v = *(const uint4*)(fb + (long long)(hy*WW + wx)*HIDD + chunk*8);
        *(uint4*)&Ls[rc*1024 + chunk*8] = v;
    }
    __syncthreads();

    int ph = tid >> 7, ct = tid & 127;
    int c0 = ct * 8;
    float sv[2][8];
    {
        float4 d0 = *(const float4*)(db + c0);
        float4 d1 = *(const float4*)(db + c0 + 4);
        #pragma unroll
        for (int pp = 0; pp < 2; pp++){
            sv[pp][0]=d0.x; sv[pp][1]=d0.y; sv[pp][2]=d0.z; sv[pp][3]=d0.w;
            sv[pp][4]=d1.x; sv[pp][5]=d1.y; sv[pp][6]=d1.z; sv[pp][7]=d1.w;
        }
    }
    #pragma unroll
    for (int tap = 0; tap < 9; tap++){
        int ky = tap / 3, kx = tap % 3;
        float4 w0v = *(const float4*)(wT + tap*1024 + c0);
        float4 w1v = *(const float4*)(wT + tap*1024 + c0 + 4);
        float wv[8] = {w0v.x,w0v.y,w0v.z,w0v.w,w1v.x,w1v.y,w1v.z,w1v.w};
        #pragma unroll
        for (int pp = 0; pp < 2; pp++){
            int pos_local = 2*ph + pp;
            short8 val = *(const short8*)&Ls[(ky*6 + pos_local + kx)*1024 + c0];
            #pragma unroll
            for (int i = 0; i < 8; i++){
                float fv = bu((unsigned short)val[i]);
                sv[pp][i] += fv * wv[i];
                if (tap == 4) sv[pp][i] += fv;
            }
        }
    }
    #pragma unroll
    for (int pp = 0; pp < 2; pp++){
        float s = 0.f, ss = 0.f;
        #pragma unroll
        for (int i = 0; i < 8; i++){ s += sv[pp][i]; ss += sv[pp][i]*sv[pp][i]; }
        r1[ph][pp][ct] = s; r2[ph][pp][ct] = ss;
    }
    __syncthreads();
    for (int st = 64; st > 0; st >>= 1){
        if (ct < st){
            #pragma unroll
            for (int pp = 0; pp < 2; pp++){
                r1[ph][pp][ct] += r1[ph][pp][ct+st];
                r2[ph][pp][ct] += r2[ph][pp][ct+st];
            }
        }
        __syncthreads();
    }
    float4 g0 = *(const float4*)(lg + c0), g1 = *(const float4*)(lg + c0 + 4);
    float4 b0 = *(const float4*)(lb + c0), b1 = *(const float4*)(lb + c0 + 4);
    float gg[8] = {g0.x,g0.y,g0.z,g0.w,g1.x,g1.y,g1.z,g1.w};
    float bb[8] = {b0.x,b0.y,b0.z,b0.w,b1.x,b1.y,b1.z,b1.w};
    #pragma unroll
    for (int pp = 0; pp < 2; pp++){
        int pos_local = 2*ph + pp;
        long long n = (long long)b*NPOS + h*WW + (w0 + pos_local);
        float mean = r1[ph][pp][0] * (1.f/HIDD);
        float var  = r2[ph][pp][0] * (1.f/HIDD) - mean*mean;
        float inv  = rsqrtf(var + 1e-5f);
        union { uint4 u; unsigned short us[8]; } ov;
        #pragma unroll
        for (int i = 0; i < 8; i++){
            float o = (sv[pp][i]-mean)*inv*gg[i] + bb[i];
            o = 0.5f*o*(1.f + erff(o*0.70710678118654752f));
            ov.us[i] = bfbits(o);
        }
        *(uint4*)(out + n*HIDD + c0) = ov.u;
    }
}

// ---------------- channel-attn: per-channel sum-sq over N ----------------
__global__ __launch_bounds__(256) void ssq_p1(const bf16* __restrict__ qkv, float* __restrict__ lss){
    __shared__ float red[4][64][8];
    int b = blockIdx.x / NCHUNK, ch = blockIdx.x % NCHUNK;
    int tid = threadIdx.x;
    int col = (tid & 63) * 8;
    int rg = tid >> 6;
    float s[8] = {0,0,0,0,0,0,0,0};
    for (int r = rg*16; r < rg*16 + 16; r++){
        long long row = (long long)(b*NPOS + ch*64 + r);
        union { uint4 u; unsigned short us[8]; } v;
        v.u = *(const uint4*)(qkv + row*768 + col);
        #pragma unroll
        for (int i = 0; i < 8; i++){ float f = bu(v.us[i]); s[i] += f*f; }
    }
    #pragma unroll
    for (int i = 0; i < 8; i++) red[rg][tid & 63][i] = s[i];
    __syncthreads();
    if (tid < 64){
        #pragma unroll
        for (int i = 0; i < 8; i++){
            float t = red[0][tid][i] + red[1][tid][i] + red[2][tid][i] + red[3][tid][i];
            lss[(long long)blockIdx.x*512 + tid*8 + i] = t;
        }
    }
}
__global__ __launch_bounds__(256) void ssq_p2(const float* __restrict__ lss, float* __restrict__ invn){
    int b = blockIdx.x; int c = blockIdx.y*256 + threadIdx.x;
    float s = 0.f;
    for (int ch = 0; ch < NCHUNK; ch++) s += lss[((long long)b*NCHUNK+ch)*512 + c];
    invn[b*512 + c] = 1.f / fmaxf(sqrtf(s), 1e-12f);
}

// ---------------- channel-attn QK partials ----------------
__global__ __launch_bounds__(256) void chanattn_qk_part(const bf16* __restrict__ qkv, const float* __restrict__ invn,
                                                        float* __restrict__ part){
    __shared__ float qs[64][36];
    __shared__ float ks[64][36];
    int bz = blockIdx.x;               // (b*8+hh)*TNS + s
    int bh = bz / TNS, s = bz % TNS;
    int b = bh >> 3, hh = bh & 7;
    int tid = threadIdx.x;
    int d = tid >> 3, e0 = (tid & 7) * 4;
    int sr = tid >> 2, sc8 = (tid & 3) * 8;
    float invq[8], invk[8];
    {
        float4 a0 = *(const float4*)(invn + b*512 + hh*32 + sc8);
        float4 a1 = *(const float4*)(invn + b*512 + hh*32 + sc8 + 4);
        float4 b0 = *(const float4*)(invn + b*512 + 256 + hh*32 + sc8);
        float4 b1 = *(const float4*)(invn + b*512 + 256 + hh*32 + sc8 + 4);
        invq[0]=a0.x; invq[1]=a0.y; invq[2]=a0.z; invq[3]=a0.w;
        invq[4]=a1.x; invq[5]=a1.y; invq[6]=a1.z; invq[7]=a1.w;
        invk[0]=b0.x; invk[1]=b0.y; invk[2]=b0.z; invk[3]=b0.w;
        invk[4]=b1.x; invk[5]=b1.y; invk[6]=b1.z; invk[7]=b1.w;
    }
    float acc[4] = {0.f,0.f,0.f,0.f};
    for (int it = 0; it < 7; it++){
        int n0 = s*448 + it*64;
        {
            long long rowb = (long long)(b*NPOS + n0 + sr) * 768;
            union { uint4 u; unsigned short us[8]; } qv, kv;
            qv.u = *(const uint4*)(qkv + rowb + hh*32 + sc8);
            kv.u = *(const uint4*)(qkv + rowb + 256 + hh*32 + sc8);
            #pragma unroll
            for (int i = 0; i < 8; i++){
                qs[sr][sc8+i] = bu(qv.us[i]) * invq[i];
                ks[sr][sc8+i] = bu(kv.us[i]) * invk[i];
            }
        }
        __syncthreads();
        #pragma unroll 4
        for (int r = 0; r < 64; r++){
            float qv = qs[r][d];
            #pragma unroll
            for (int j = 0; j < 4; j++) acc[j] += qv * ks[r][e0+j];
        }
        __syncthreads();
    }
    #pragma unroll
    for (int j = 0; j < 4; j++)
        part[(long long)bz*1024 + d*32 + e0 + j] = acc[j];
}
__global__ __launch_bounds__(256) void chanattn_qk_fin(const float* __restrict__ part, const float* __restrict__ temp,
                                                       float* __restrict__ attn){
    __shared__ float att_s[32][33];
    int bh = blockIdx.x;
    int hh = bh & 7;
    int tid = threadIdx.x;
    int d = tid >> 3, e0 = (tid & 7) * 4;
    float t = temp[hh];
    #pragma unroll
    for (int j = 0; j < 4; j++){
        float s = 0.f;
        for (int sp = 0; sp < TNS; sp++)
            s += part[((long long)bh*TNS + sp)*1024 + d*32 + e0 + j];
        att_s[d][e0+j] = s * t;
    }
    __syncthreads();
    if (tid < 32){
        float m = -1e30f;
        for (int e = 0; e < 32; e++) m = fmaxf(m, att_s[tid][e]);
        float s = 0.f;
        for (int e = 0; e < 32; e++){ float ev = expf(att_s[tid][e] - m); att_s[tid][e] = ev; s += ev; }
        float inv = 1.f / s;
        for (int e = 0; e < 32; e++) att_s[tid][e] *= inv;
    }
    __syncthreads();
    #pragma unroll
    for (int j = 0; j < 4; j++)
        attn[(long long)bh*1024 + d*32 + e0 + j] = att_s[d][e0+j];
}

// ---------------- combined weight: W_b[o][h*32+e] = sum_d capw[o][h*32+d]*attn[b][h][d][e] ----------------
__global__ __launch_bounds__(256) void wcomb_kernel(const float* __restrict__ capw, const float* __restrict__ attn,
                                                    bf16* __restrict__ Wb){
    __shared__ float at_s[8192];
    int b = blockIdx.x, og = blockIdx.y;
    int tid = threadIdx.x;
    #pragma unroll
    for (int j = 0; j < 8; j++)
        *(float4*)&at_s[tid*32 + j*4] = *(const float4*)(attn + (long long)b*8192 + tid*32 + j*4);
    __syncthreads();
    int o = og*32 + (tid & 31);
    int h = tid >> 5;
    float acc[32];
    #pragma unroll
    for (int e = 0; e < 32; e++) acc[e] = 0.f;
    for (int d = 0; d < 32; d++){
        float w = capw[(long long)o*256 + h*32 + d];
        const float* ar = &at_s[h*1024 + d*32];
        #pragma unroll
        for (int eq = 0; eq < 8; eq++){
            float4 av = *(const float4*)(ar + eq*4);
            acc[eq*4+0] += w*av.x; acc[eq*4+1] += w*av.y;
            acc[eq*4+2] += w*av.z; acc[eq*4+3] += w*av.w;
        }
    }
    bf16* dst = Wb + (long long)b*65536 + (long long)o*256 + h*32;
    #pragma unroll
    for (int eq = 0; eq < 4; eq++){
        union { uint4 u; unsigned short us[8]; } p;
        #pragma unroll
        for (int i = 0; i < 8; i++) p.us[i] = bfbits(acc[eq*8+i]);
        *(uint4*)(dst + eq*8) = p.u;
    }
}

// ---------------- orchestration ----------------
extern "C" void kernel_launch(void* const* d_in, const int* in_sizes, int n_in,
                              void* d_out, int out_size, void* d_ws, size_t ws_size,
                              hipStream_t stream){
    const float* x     = (const float*)d_in[0];
    const float* ln1g  = (const float*)d_in[3];
    const float* ln1b  = (const float*)d_in[4];
    const float* eakw  = (const float*)d_in[5];
    const float* eaqw  = (const float*)d_in[7];
    const float* eaqb  = (const float*)d_in[8];
    const float* eavw  = (const float*)d_in[9];
    const float* eavb  = (const float*)d_in[10];
    const float* earw  = (const float*)d_in[11];
    const float* earb  = (const float*)d_in[12];
    const float* ln2g  = (const float*)d_in[13];
    const float* ln2b  = (const float*)d_in[14];
    const float* m1w1  = (const float*)d_in[15];
    const float* m1b1  = (const float*)d_in[16];
    const float* m1dww = (const float*)d_in[17];
    const float* m1dwb = (const float*)d_in[18];
    const float* m1lg  = (const float*)d_in[19];
    const float* m1lb  = (const float*)d_in[20];
    const float* m1w2  = (const float*)d_in[21];
    const float* m1b2  = (const float*)d_in[22];
    const float* ln3g  = (const float*)d_in[23];
    const float* ln3b  = (const float*)d_in[24];
    const float* catemp= (const float*)d_in[25];
    const float* caqkvw= (const float*)d_in[26];
    const float* capw  = (const float*)d_in[27];
    const float* capb  = (const float*)d_in[28];
    const float* ln4g  = (const float*)d_in[29];
    const float* ln4b  = (const float*)d_in[30];
    const float* m2w1  = (const float*)d_in[31];
    const float* m2b1  = (const float*)d_in[32];
    const float* m2dww = (const float*)d_in[33];
    const float* m2dwb = (const float*)d_in[34];
    const float* m2lg  = (const float*)d_in[35];
    const float* m2lb  = (const float*)d_in[36];
    const float* m2w2  = (const float*)d_in[37];
    const float* m2b2  = (const float*)d_in[38];

    char* base = (char*)d_ws;
    auto alloc = [&](size_t nbytes){ char* p = base; base += (nbytes + 255) & ~(size_t)255; return p; };
    constexpr size_t SZ = (size_t)MTOT*CDIM*4;
    float* R  = (float*)alloc(SZ);
    float* A0 = (float*)alloc(SZ);
    float* A1 = (float*)alloc(SZ);
    float* B0 = (float*)alloc(SZ);
    float* B1 = (float*)alloc(SZ);
    bf16* A0b  = (bf16*)A0;                 // s1: ln1 out, then (after kq/v GEMMs) k-softmax bf16
    bf16* kb   = (bf16*)A0;                 //     same region, second life
    bf16* qb   = A0b + (size_t)MTOT*CDIM;   // s1: q softmax out (second half A0)
    bf16* vb   = (bf16*)A1;                 // s1: v bf16
    float* KQ  = B0;                        // s1: fused k|q f32 [MTOT,512] spans B0..B1
    bf16* attb = (bf16*)B0;                 // s1: att out (KQ dead)
    bf16* l2b  = (bf16*)A1;                 // s2: ln2 out
    bf16* F    = (bf16*)B0;                 // s2/s4: fc1 out
    bf16* G    = (bf16*)A0;                 // s2/s4: dwconv out
    bf16* l3b  = (bf16*)B0;                 // s3: ln3 out
    bf16* Qb   = (bf16*)A0;                 // s3: qkv
    bf16* l4b  = (bf16*)A0;                 // s4: ln4 out
    bf16* ctxb = (bf16*)alloc((size_t)BATCH*CDIM*CDIM*2);
    float* lmax = (float*)alloc((size_t)BATCH*NCHUNK*CDIM*4);
    float* lsum = (float*)alloc((size_t)BATCH*NCHUNK*CDIM*4);
    float* gmax = (float*)alloc((size_t)BATCH*CDIM*4);
    float* ginv = (float*)alloc((size_t)BATCH*CDIM*4);
    float* lss  = (float*)alloc((size_t)BATCH*NCHUNK*512*4);
    float* invn = (float*)alloc((size_t)BATCH*512*4);
    float* attnb= (float*)alloc((size_t)BATCH*8*32*32*4);
    float* ptn  = (float*)alloc((size_t)BATCH*TNS*CDIM*CDIM*4);
    float* pqk  = (float*)alloc((size_t)BATCH*8*TNS*1024*4);
    bf16* wbuf  = (bf16*)alloc((size_t)1572864*2);
    float* wT1  = (float*)alloc((size_t)9216*4);
    float* wT2  = (float*)alloc((size_t)9216*4);
    bf16* Wcb   = (bf16*)alloc((size_t)BATCH*CDIM*CDIM*2);

    bf16* kqw_b    = wbuf;                  // [512,256]: rows 0-255 k, 256-511 q
    bf16* eavw_b   = wbuf + 131072;
    bf16* earw_b   = wbuf + 196608;
    bf16* m1w1_b   = wbuf + 262144;
    bf16* m1w2_b   = wbuf + 524288;
    bf16* caqkvw_b = wbuf + 786432;
    bf16* m2w1_b   = wbuf + 1048576;
    bf16* m2w2_b   = wbuf + 1310720;

    dim3 blk(256);
    constexpr int MB = MTOT/128;            // 196
    long long sA1 = (long long)NPOS*CDIM;
    long long sB1 = (long long)CDIM*CDIM;

    // ---- weight prep ----
    {
        WArgs wa;
        const float* srcs[10] = {eakw, eaqw, eavw, earw, m1w1, m1w2, caqkvw, m2w1, m2w2, m2w2};
        bf16* dsts[10] = {kqw_b, kqw_b + 65536, eavw_b, earw_b, m1w1_b, m1w2_b, caqkvw_b, m2w1_b, m2w2_b, m2w2_b};
        int ns[10] = {65536, 65536, 65536, 65536, 262144, 262144, 196608, 262144, 262144, 0};
        for (int i = 0; i < 10; i++){ wa.src[i]=srcs[i]; wa.dst[i]=dsts[i]; wa.n[i]=ns[i]; }
        wcvt_kernel<<<dim3(128,10), blk, 0, stream>>>(wa);
        wtrans_kernel<<<dim3(36,2), blk, 0, stream>>>(m1dww, m2dww, wT1, wT2);
    }

    // ---- Stage 1: EfficientAttention ----
    ln4_kernel<bf16><<<MTOT/4, blk, 0, stream>>>(x, ln1g, ln1b, A0b);
    mfma_gemm<float><<<dim3(4,MB,1), blk, 0, stream>>>(A0b, kqw_b, nullptr, nullptr, KQ, MTOT, 512, 256, 256, 0,0,0,0); // k|q (k bias dropped: softmax-N invariant; q bias added in rowsm)
    mfma_gemm<bf16><<<dim3(2,MB,1), blk, 0, stream>>>(A0b, eavw_b, eavb, nullptr, vb, MTOT, 256, 256, 256, 0,0,0,0);
    rowsm4b_kernel<<<MTOT/4, blk, 0, stream>>>(KQ, eaqb, qb);
    colsm_p1<<<BATCH*NCHUNK, blk, 0, stream>>>(KQ, lmax, lsum);
    colsm_p2<<<BATCH, blk, 0, stream>>>(lmax, lsum, gmax, ginv);
    colsm_p3<<<MTOT, blk, 0, stream>>>(KQ, kb, gmax, ginv);             // kb overwrites dead ln1-out region
    gemm_tn_mfma<<<dim3(2,2,BATCH*TNS), blk, 0, stream>>>(vb, kb, ptn);
    ctx_reduce<<<(BATCH*65536)/256, blk, 0, stream>>>(ptn, ctxb);
    mfma_gemm<bf16><<<dim3(2,25,BATCH), blk, 0, stream>>>(qb, ctxb, nullptr, nullptr, attb,
            NPOS, 256, 256, 256, sA1, sB1, sA1, 0);
    mfma_gemm<float><<<dim3(2,MB,1), blk, 0, stream>>>(attb, earw_b, earb, x, R, MTOT, 256, 256, 256, 0,0,0,0);

    // ---- Stage 2: MixFFN #1 ----
    ln4_kernel<bf16><<<MTOT/4, blk, 0, stream>>>(R, ln2g, ln2b, l2b);
    mfma_gemm<bf16><<<dim3(8,MB,1), blk, 0, stream>>>(l2b, m1w1_b, m1b1, nullptr, F, MTOT, 1024, 256, 256, 0,0,0,0);
    dwconv_ln_gelu_kernel<<<BATCH*HH*14, blk, 0, stream>>>(F, wT1, m1dwb, m1lg, m1lb, G);
    mfma_gemm<float><<<dim3(2,MB,1), blk, 0, stream>>>(G, m1w2_b, m1b2, R, R, MTOT, 256, 1024, 1024, 0,0,0,0);

    // ---- Stage 3: ChannelAttention ----
    ln4_kernel<bf16><<<MTOT/4, blk, 0, stream>>>(R, ln3g, ln3b, l3b);
    mfma_gemm<bf16><<<dim3(6,MB,1), blk, 0, stream>>>(l3b, caqkvw_b, nullptr, nullptr, Qb, MTOT, 768, 256, 256, 0,0,0,0);
    ssq_p1<<<BATCH*NCHUNK, blk, 0, stream>>>(Qb, lss);
    ssq_p2<<<dim3(BATCH,2), blk, 0, stream>>>(lss, invn);
    chanattn_qk_part<<<BATCH*8*TNS, blk, 0, stream>>>(Qb, invn, pqk);
    chanattn_qk_fin<<<BATCH*8, blk, 0, stream>>>(pqk, catemp, attnb);
    wcomb_kernel<<<dim3(BATCH,8), blk, 0, stream>>>(capw, attnb, Wcb);
    mfma_gemm<float><<<dim3(2,25,BATCH), blk, 0, stream>>>(Qb + 512, Wcb, capb, R, R,
            NPOS, 256, 256, 768, (long long)NPOS*768, sB1, sA1, sA1);

    // ---- Stage 4: MixFFN #2 ----
    ln4_kernel<bf16><<<MTOT/4, blk, 0, stream>>>(R, ln4g, ln4b, l4b);
    mfma_gemm<bf16><<<dim3(8,MB,1), blk, 0, stream>>>(l4b, m2w1_b, m2b1, nullptr, F, MTOT, 1024, 256, 256, 0,0,0,0);
    dwconv_ln_gelu_kernel<<<BATCH*HH*14, blk, 0, stream>>>(F, wT2, m2dwb, m2lg, m2lb, G);
    mfma_gemm<float><<<dim3(2,MB,1), blk, 0, stream>>>(G, m2w2_b, m2b2, R, (float*)d_out, MTOT, 256, 1024, 1024, 0,0,0,0);
}